// Round 13
// baseline (2059.431 us; speedup 1.0000x reference)
//
#include <hip/hip_runtime.h>
#include <hip/hip_bf16.h>
#include <math.h>

typedef unsigned short ushort_t;
typedef short short8 __attribute__((ext_vector_type(8)));
typedef float f32x4 __attribute__((ext_vector_type(4)));

#define N_TOK 512
#define EMBED 1024
#define INTER 4096
#define NCAT  5120   /* INTER + EMBED */
#define MROWS 24576  /* 48 * 512 */

__device__ __forceinline__ ushort_t f2bf(float f) {
  union { float f; unsigned int u; } c; c.f = f;
  unsigned int u = c.u;
  unsigned int r = u + 0x7fffu + ((u >> 16) & 1u);
  return (ushort_t)(r >> 16);
}

__device__ __forceinline__ void gld_lds16(const void* g, void* l) {
  __builtin_amdgcn_global_load_lds(
      (const __attribute__((address_space(1))) void*)g,
      (__attribute__((address_space(3))) void*)l, 16, 0, 0);
}

// ---- merged prep kernels ------------------------------------------------
__global__ void prep_w(const float* __restrict__ Wl, const float* __restrict__ Wr,
                       const float* __restrict__ Wo,
                       const float* __restrict__ bl, const float* __restrict__ br,
                       ushort_t* __restrict__ wout,
                       ushort_t* __restrict__ w0, ushort_t* __restrict__ w1,
                       ushort_t* __restrict__ w2, float* __restrict__ bcat) {
  int i = blockIdx.x * 256 + threadIdx.x;
  if (i < NCAT) { bcat[i] = (i < INTER) ? bl[i] : br[i - INTER]; return; }
  i -= NCAT;
  if (i < EMBED * INTER) { wout[i] = f2bf(Wo[i]); return; }
  i -= EMBED * INTER;
  ushort_t* dst; int Kpad, P3;
  if (i < NCAT * 64)            { dst = w0; Kpad = 64;  P3 = 48; }
  else if (i < NCAT * 160)      { i -= NCAT * 64;  dst = w1; Kpad = 96;  P3 = 96; }
  else if (i < NCAT * 352)      { i -= NCAT * 160; dst = w2; Kpad = 192; P3 = 192; }
  else return;
  const int r = i / Kpad, j = i - r * Kpad;
  float v = 0.f;
  if (j < P3) {
    float scale = 96.0f / (float)P3;
    float src = (j + 0.5f) * scale - 0.5f;
    src = fminf(fmaxf(src, 0.0f), 95.0f);
    int i0 = (int)src;
    int i1 = min(i0 + 1, 95);
    float tt = src - (float)i0;
    const float* Wrow = (r < INTER) ? (Wl + (size_t)r * 96)
                                    : (Wr + (size_t)(r - INTER) * 96);
    v = Wrow[i0] * (1.f - tt) + Wrow[i1] * tt;
  }
  dst[i] = f2bf(v);
}

__global__ void prep_x(const float* __restrict__ x0, const float* __restrict__ m0,
                       const float* __restrict__ t0,
                       const float* __restrict__ x1, const float* __restrict__ m1,
                       const float* __restrict__ t1,
                       const float* __restrict__ x2, const float* __restrict__ m2,
                       const float* __restrict__ t2,
                       ushort_t* __restrict__ d0, ushort_t* __restrict__ d1,
                       ushort_t* __restrict__ d2) {
  int i = blockIdx.x * 256 + threadIdx.x;
  const float *x, *m, *t; ushort_t* dst; int p, Kpad;
  if (i < 8192 * 64)            { x = x0; m = m0; t = t0; dst = d0; p = 16; Kpad = 64; }
  else if (i < 8192 * 160)      { i -= 8192 * 64;  x = x1; m = m1; t = t1; dst = d1; p = 32; Kpad = 96; }
  else if (i < 8192 * 352)      { i -= 8192 * 160; x = x2; m = m2; t = t2; dst = d2; p = 64; Kpad = 192; }
  else return;
  const int r = i / Kpad, j = i - r * Kpad;
  float v = 0.f;
  const int p3 = 3 * p;
  if (j < p3) {
    size_t base = (size_t)r * p;
    if (j < p)           v = x[base + j];
    else if (j < 2 * p)  v = m[base + j - p];
    else                 v = t[base + j - 2 * p];
  }
  dst[i] = f2bf(v);
}

// ---- phase-1: merged 3-group 128x128 GEMM (R3/R7 interior, proven) ------
__global__ __launch_bounds__(256)
void gemm128p1g(const ushort_t* __restrict__ A0, const ushort_t* __restrict__ A1,
                const ushort_t* __restrict__ A2,
                const ushort_t* __restrict__ B0w, const ushort_t* __restrict__ B1w,
                const ushort_t* __restrict__ B2w,
                const float* __restrict__ bias,
                ushort_t* __restrict__ hidden, float* __restrict__ outp,
                const int* __restrict__ i0, const int* __restrict__ i1,
                const int* __restrict__ i2) {
  __shared__ __align__(16) ushort_t lA[2][128 * 32];
  __shared__ __align__(16) ushort_t lB[2][128 * 32];
  const int t = threadIdx.x;
  const int wave = t >> 6, lane = t & 63;
  const int gm = blockIdx.x >> 6;             // group 0/1/2
  const int tm = (blockIdx.x & 63) * 128;     // within-group row tile
  const int tn = blockIdx.y * 128;
  const ushort_t* A = (gm == 0) ? A0 : (gm == 1) ? A1 : A2;
  const ushort_t* B = (gm == 0) ? B0w : (gm == 1) ? B1w : B2w;
  const int* idxg   = (gm == 0) ? i0 : (gm == 1) ? i1 : i2;
  const int Kpad    = (gm == 0) ? 64 : (gm == 1) ? 96 : 192;

  const int chunk = wave * 2;
  const int srow = chunk * 16 + (lane >> 2);
  const int scol = (((lane & 3) ^ ((lane >> 3) & 3)) * 8);
  const ushort_t* gA0 = A + (size_t)(tm + srow) * Kpad + scol;
  const ushort_t* gA1 = gA0 + (size_t)16 * Kpad;
  const ushort_t* gB0 = B + (size_t)(tn + srow) * Kpad + scol;
  const ushort_t* gB1 = gB0 + (size_t)16 * Kpad;
  const int ldsOff0 = chunk * 512;
  const int ldsOff1 = ldsOff0 + 512;

  const int wr = wave >> 1, wc = wave & 1;
  const f32x4 zero = {0.f, 0.f, 0.f, 0.f};
  f32x4 acc[4][4];
#pragma unroll
  for (int m2 = 0; m2 < 4; ++m2)
#pragma unroll
    for (int n2 = 0; n2 < 4; ++n2) acc[m2][n2] = zero;

  const int xf = ((lane & 15) >> 1) & 3;
  const int fcol = (((lane >> 4) ^ xf)) * 8;
  const int aoff = (wr * 64 + (lane & 15)) * 32 + fcol;
  const int boff = (wc * 64 + (lane & 15)) * 32 + fcol;

  const int nk = Kpad >> 5;
  gld_lds16(gA0, &lA[0][ldsOff0]); gld_lds16(gA1, &lA[0][ldsOff1]);
  gld_lds16(gB0, &lB[0][ldsOff0]); gld_lds16(gB1, &lB[0][ldsOff1]);
  gA0 += 32; gA1 += 32; gB0 += 32; gB1 += 32;

  for (int kk = 0; kk < nk; ++kk) {
    const int cur = kk & 1;
    if (kk + 1 < nk) {
      const int nxt = cur ^ 1;
      gld_lds16(gA0, &lA[nxt][ldsOff0]); gld_lds16(gA1, &lA[nxt][ldsOff1]);
      gld_lds16(gB0, &lB[nxt][ldsOff0]); gld_lds16(gB1, &lB[nxt][ldsOff1]);
      gA0 += 32; gA1 += 32; gB0 += 32; gB1 += 32;
      asm volatile("s_waitcnt vmcnt(4)" ::: "memory");
    } else {
      asm volatile("s_waitcnt vmcnt(0)" ::: "memory");
    }
    __builtin_amdgcn_s_barrier();
    asm volatile("" ::: "memory");

    const ushort_t* pa = &lA[cur][0] + aoff;
    const ushort_t* pb = &lB[cur][0] + boff;
    short8 aF[4], bF[4];
#pragma unroll
    for (int m2 = 0; m2 < 4; ++m2) aF[m2] = *(const short8*)(pa + m2 * 16 * 32);
#pragma unroll
    for (int n2 = 0; n2 < 4; ++n2) bF[n2] = *(const short8*)(pb + n2 * 16 * 32);
#pragma unroll
    for (int m2 = 0; m2 < 4; ++m2)
#pragma unroll
      for (int n2 = 0; n2 < 4; ++n2)
        acc[m2][n2] = __builtin_amdgcn_mfma_f32_16x16x32_bf16(
            aF[m2], bF[n2], acc[m2][n2], 0, 0, 0);
    __builtin_amdgcn_s_barrier();
    asm volatile("" ::: "memory");
  }

  const int layer = idxg[tm >> 9];
  const int rowBase = layer * N_TOK + (tm & (N_TOK - 1));

#pragma unroll
  for (int m2 = 0; m2 < 4; ++m2) {
#pragma unroll
    for (int n2 = 0; n2 < 4; ++n2) {
      const int colg = tn + wc * 64 + n2 * 16 + (lane & 15);
      const float bv = bias[colg];
#pragma unroll
      for (int r = 0; r < 4; ++r) {
        const int rowl = wr * 64 + m2 * 16 + (lane >> 4) * 4 + r;
        const float v = acc[m2][n2][r];
        const int grow = rowBase + rowl;
        if (colg < INTER) {
          float h = v + bv;
          h = h / (1.f + expf(-h));
          hidden[(size_t)grow * INTER + colg] = f2bf(h);
        } else {
          outp[(size_t)grow * EMBED + (colg - INTER)] = v + bv;
        }
      }
    }
  }
}

// ---- phase-2: 192x128 GEMM, BK=32, 4 blocks/CU co-resident -------------
// A = hidden [24576][4096] bf16, B = wout [1024][4096] bf16 (B^T layout).
// Grid 1024 = 8 xcd * 16 mtl * 8 nt (nt fastest). LDS per block: 2 buf x
// (A 12KB [192r][64B] + B 8KB [128r][64B]) = 40960 B -> EXACTLY 4 blocks/CU
// (160 KiB), 16 waves/CU, one fully-resident balanced round.
// Same 0-conflict XOR chunk swizzle and minimal-barrier schedule as R10.
// Ledger (5 loads/KT/thread = A3+B2), KT t in buf t&1:
//   prologue: A0,B0 -> buf0; A1 -> buf1; WAITV(3); BARR
//   per KT: reads(6A+4B) ; stage B(t+1) -> buf^1 ; MFMA nh0 ; BARR ;
//           stage A(t+2) -> buf ; MFMA nh1 ; WAITV(3) ; BARR
//   (enter: A(t+1).3 ; +B(t+1).2 +A(t+2).3 = 8 ; WAITV(3) leaves A(t+2))
#define P2BUF 20480
#define P2BOFF 12288

__global__ __launch_bounds__(256, 4)
void gemm192k32(const ushort_t* __restrict__ A, const ushort_t* __restrict__ Bw,
                const float* __restrict__ bias, float* __restrict__ outp) {
  __shared__ __align__(16) char smem[2 * P2BUF];
  const int tid = threadIdx.x;
  const int w = tid >> 6, l = tid & 63;

  const int L = blockIdx.x;
  const int xcd = L & 7, j = L >> 3;          // j in [0,128)
  const int nt = j & 7, mtl = j >> 3;         // nt fastest: A-slab reuse
  const int tm = (xcd * 16 + mtl) * 192, tn = nt * 128;

  // staging source pointers (pre-swizzled global, linear LDS dest)
  const ushort_t* pA[3]; int dA[3];
#pragma unroll
  for (int jj = 0; jj < 3; ++jj) {
    const int q = w * 3 + jj;                 // 0..11 (12 x 16 rows = 192)
    const int row = q * 16 + (l >> 2);
    const int c = (l & 3) ^ ((row >> 1) & 3);
    pA[jj] = A + (size_t)(tm + row) * 4096 + c * 8;
    dA[jj] = q * 1024;
  }
  const ushort_t* pB[2]; int dB[2];
#pragma unroll
  for (int jj = 0; jj < 2; ++jj) {
    const int q = w * 2 + jj;                 // 0..7 (8 x 16 rows = 128)
    const int row = q * 16 + (l >> 2);
    const int c = (l & 3) ^ ((row >> 1) & 3);
    pB[jj] = Bw + (size_t)(tn + row) * 4096 + c * 8;
    dB[jj] = P2BOFF + q * 1024;
  }

#define STGA3(BB) do { _Pragma("unroll") for (int jj = 0; jj < 3; ++jj) \
    gld_lds16(pA[jj], smem + (BB) + dA[jj]); \
    _Pragma("unroll") for (int jj = 0; jj < 3; ++jj) pA[jj] += 32; } while (0)
#define STGB2(BB) do { _Pragma("unroll") for (int jj = 0; jj < 2; ++jj) \
    gld_lds16(pB[jj], smem + (BB) + dB[jj]); \
    _Pragma("unroll") for (int jj = 0; jj < 2; ++jj) pB[jj] += 32; } while (0)

  // fragment read bases (swizzled read, conflict-free — R3-proven)
  const int wr = w >> 1, wc = w & 1;          // 2M x 2N, wave tile 96x64
  const int xl = ((l & 15) >> 1) & 3;
  const int cx = ((l >> 4) ^ xl) * 16;
  const int aBase = (wr * 96 + (l & 15)) * 64 + cx;
  const int bBase = P2BOFF + (wc * 64 + (l & 15)) * 64 + cx;

  f32x4 acc[6][4];
  const f32x4 zero = {0.f, 0.f, 0.f, 0.f};
#pragma unroll
  for (int m = 0; m < 6; ++m)
#pragma unroll
    for (int n = 0; n < 4; ++n) acc[m][n] = zero;
  short8 aF[6], bFa[2], bFb[2];

#define LDA6(BB) do { _Pragma("unroll") for (int mp = 0; mp < 6; ++mp) \
    aF[mp] = *(const short8*)(smem + (BB) + mp * 1024 + aBase); } while (0)
#define LDB2(D, BB, NH) do { _Pragma("unroll") for (int np = 0; np < 2; ++np) \
    D[np] = *(const short8*)(smem + (BB) + (NH) * 2048 + np * 1024 + bBase); } while (0)
#define QUAD12(NH, FB) do { _Pragma("unroll") for (int mp = 0; mp < 6; ++mp) { \
    _Pragma("unroll") for (int np = 0; np < 2; ++np) \
      acc[mp][(NH)*2+np] = __builtin_amdgcn_mfma_f32_16x16x32_bf16( \
          aF[mp], FB[np], acc[mp][(NH)*2+np], 0, 0, 0); } } while (0)
#define BARR do { __builtin_amdgcn_s_barrier(); asm volatile("" ::: "memory"); } while (0)
#define WAITV(N) do { asm volatile("s_waitcnt vmcnt(" #N ")" ::: "memory"); \
    __builtin_amdgcn_sched_barrier(0); } while (0)
#define PRIO1 __builtin_amdgcn_s_setprio(1)
#define PRIO0 __builtin_amdgcn_s_setprio(0)

  // prologue: A0,B0 -> buf0; A1 -> buf1; drain A0,B0 (leave A1 in flight)
  STGA3(0); STGB2(0);
  STGA3(P2BUF);
  WAITV(3);
  BARR;

  const int nit2 = 64;                         // 128 KTs, 2 per iteration
  for (int t2 = 0; t2 < nit2; ++t2) {
    const bool morA = (t2 + 1 < nit2);
    // ---- KT even (buf0) ----
    LDA6(0); LDB2(bFa, 0, 0); LDB2(bFb, 0, 1);
    STGB2(P2BUF);                              // B(t+1) -> buf1 (always)
    PRIO1; QUAD12(0, bFa); PRIO0;
    BARR;                                      // seals all waves' buf0 reads
    if (morA) STGA3(0);                        // A(t+2) -> buf0
    PRIO1; QUAD12(1, bFb); PRIO0;
    if (morA) { WAITV(3); } else { WAITV(0); } // A(t+1)+B(t+1) landed
    BARR;
    // ---- KT odd (buf1) ----
    LDA6(P2BUF); LDB2(bFa, P2BUF, 0); LDB2(bFb, P2BUF, 1);
    if (morA) STGB2(0);                        // B(t+2) -> buf0
    PRIO1; QUAD12(0, bFa); PRIO0;
    BARR;
    if (morA) STGA3(P2BUF);                    // A(t+3) -> buf1
    PRIO1; QUAD12(1, bFb); PRIO0;
    if (morA) { WAITV(3); } else { WAITV(0); }
    BARR;
  }

  // ---- epilogue: out += acc + bias (single writer, no atomics) ----
  float bv[4];
#pragma unroll
  for (int n = 0; n < 4; ++n)
    bv[n] = bias[tn + wc * 64 + (n >> 1) * 32 + (n & 1) * 16 + (l & 15)];
#pragma unroll
  for (int m = 0; m < 6; ++m) {
    const int row = tm + wr * 96 + m * 16 + (l >> 4) * 4;
#pragma unroll
    for (int n = 0; n < 4; ++n) {
      const int col = tn + wc * 64 + (n >> 1) * 32 + (n & 1) * 16 + (l & 15);
      float* po = outp + (size_t)row * EMBED + col;
#pragma unroll
      for (int ri = 0; ri < 4; ++ri)
        po[(size_t)ri * EMBED] += acc[m][n][ri] + bv[n];
    }
  }
}

// ---- launch -------------------------------------------------------------

extern "C" void kernel_launch(void* const* d_in, const int* in_sizes, int n_in,
                              void* d_out, int out_size, void* d_ws, size_t ws_size,
                              hipStream_t stream) {
  const float* xg[3] = {(const float*)d_in[0], (const float*)d_in[3], (const float*)d_in[6]};
  const float* mg[3] = {(const float*)d_in[1], (const float*)d_in[4], (const float*)d_in[7]};
  const float* tg[3] = {(const float*)d_in[2], (const float*)d_in[5], (const float*)d_in[8]};
  const int* idxg[3] = {(const int*)d_in[9], (const int*)d_in[10], (const int*)d_in[11]};
  const float* W_lin = (const float*)d_in[12];
  const float* b_lin = (const float*)d_in[13];
  const float* W_res = (const float*)d_in[14];
  const float* b_res = (const float*)d_in[15];
  const float* W_out = (const float*)d_in[16];
  const float* b_out = (const float*)d_in[17];
  float* out = (float*)d_out;

  char* ws = (char*)d_ws;
  size_t off = 0;
  auto alloc = [&](size_t b) -> char* {
    size_t o = (off + 255) & ~(size_t)255;
    off = o + b;
    return ws + o;
  };

  ushort_t* hidden = (ushort_t*)alloc((size_t)MROWS * INTER * 2);   // 201 MB
  const int Kp[3] = {64, 96, 192};
  ushort_t* xsw[3];
  ushort_t* wcat[3];
  for (int g = 0; g < 3; ++g) xsw[g]  = (ushort_t*)alloc((size_t)8192 * Kp[g] * 2);
  for (int g = 0; g < 3; ++g) wcat[g] = (ushort_t*)alloc((size_t)NCAT * Kp[g] * 2);
  ushort_t* wout = (ushort_t*)alloc((size_t)EMBED * INTER * 2);     // 8 MB
  float* bcat = (float*)alloc((size_t)NCAT * 4);

  // merged preps: 2 dispatches
  const int wTotal = NCAT + EMBED * INTER + NCAT * 352;   // 6,001,664
  prep_w<<<(wTotal + 255) / 256, 256, 0, stream>>>(
      W_lin, W_res, W_out, b_lin, b_res, wout, wcat[0], wcat[1], wcat[2], bcat);
  const int xTotal = 8192 * 352;                          // 2,883,584
  prep_x<<<(xTotal + 255) / 256, 256, 0, stream>>>(
      xg[0], mg[0], tg[0], xg[1], mg[1], tg[1], xg[2], mg[2], tg[2],
      xsw[0], xsw[1], xsw[2]);

  // phase 1: all 3 groups in ONE dispatch: [8192 x Kp] @ [5120 x Kp]^T each
  gemm128p1g<<<dim3(192, 40), 256, 0, stream>>>(
      xsw[0], xsw[1], xsw[2], wcat[0], wcat[1], wcat[2], bcat,
      hidden, out, idxg[0], idxg[1], idxg[2]);
  // phase 2: [24576 x 4096] @ [1024 x 4096]^T, full K, out += acc + b_out
  gemm192k32<<<dim3(1024), 256, 0, stream>>>(hidden, wout, b_out, out);
}

// Round 14
// 392.378 us; speedup vs baseline: 5.2486x; 5.2486x over previous
//
#include <hip/hip_runtime.h>
#include <hip/hip_bf16.h>
#include <math.h>

typedef unsigned short ushort_t;
typedef short short8 __attribute__((ext_vector_type(8)));
typedef float f32x4 __attribute__((ext_vector_type(4)));
typedef float f32x16 __attribute__((ext_vector_type(16)));

#define N_TOK 512
#define EMBED 1024
#define INTER 4096
#define NCAT  5120   /* INTER + EMBED */
#define MROWS 24576  /* 48 * 512 */

__device__ __forceinline__ ushort_t f2bf(float f) {
  union { float f; unsigned int u; } c; c.f = f;
  unsigned int u = c.u;
  unsigned int r = u + 0x7fffu + ((u >> 16) & 1u);
  return (ushort_t)(r >> 16);
}

__device__ __forceinline__ void gld_lds16(const void* g, void* l) {
  __builtin_amdgcn_global_load_lds(
      (const __attribute__((address_space(1))) void*)g,
      (__attribute__((address_space(3))) void*)l, 16, 0, 0);
}

// ---- merged prep kernels ------------------------------------------------
__global__ void prep_w(const float* __restrict__ Wl, const float* __restrict__ Wr,
                       const float* __restrict__ Wo,
                       const float* __restrict__ bl, const float* __restrict__ br,
                       ushort_t* __restrict__ wout,
                       ushort_t* __restrict__ w0, ushort_t* __restrict__ w1,
                       ushort_t* __restrict__ w2, float* __restrict__ bcat) {
  int i = blockIdx.x * 256 + threadIdx.x;
  if (i < NCAT) { bcat[i] = (i < INTER) ? bl[i] : br[i - INTER]; return; }
  i -= NCAT;
  if (i < EMBED * INTER) { wout[i] = f2bf(Wo[i]); return; }
  i -= EMBED * INTER;
  ushort_t* dst; int Kpad, P3;
  if (i < NCAT * 64)            { dst = w0; Kpad = 64;  P3 = 48; }
  else if (i < NCAT * 160)      { i -= NCAT * 64;  dst = w1; Kpad = 96;  P3 = 96; }
  else if (i < NCAT * 352)      { i -= NCAT * 160; dst = w2; Kpad = 192; P3 = 192; }
  else return;
  const int r = i / Kpad, j = i - r * Kpad;
  float v = 0.f;
  if (j < P3) {
    float scale = 96.0f / (float)P3;
    float src = (j + 0.5f) * scale - 0.5f;
    src = fminf(fmaxf(src, 0.0f), 95.0f);
    int i0 = (int)src;
    int i1 = min(i0 + 1, 95);
    float tt = src - (float)i0;
    const float* Wrow = (r < INTER) ? (Wl + (size_t)r * 96)
                                    : (Wr + (size_t)(r - INTER) * 96);
    v = Wrow[i0] * (1.f - tt) + Wrow[i1] * tt;
  }
  dst[i] = f2bf(v);
}

__global__ void prep_x(const float* __restrict__ x0, const float* __restrict__ m0,
                       const float* __restrict__ t0,
                       const float* __restrict__ x1, const float* __restrict__ m1,
                       const float* __restrict__ t1,
                       const float* __restrict__ x2, const float* __restrict__ m2,
                       const float* __restrict__ t2,
                       ushort_t* __restrict__ d0, ushort_t* __restrict__ d1,
                       ushort_t* __restrict__ d2) {
  int i = blockIdx.x * 256 + threadIdx.x;
  const float *x, *m, *t; ushort_t* dst; int p, Kpad;
  if (i < 8192 * 64)            { x = x0; m = m0; t = t0; dst = d0; p = 16; Kpad = 64; }
  else if (i < 8192 * 160)      { i -= 8192 * 64;  x = x1; m = m1; t = t1; dst = d1; p = 32; Kpad = 96; }
  else if (i < 8192 * 352)      { i -= 8192 * 160; x = x2; m = m2; t = t2; dst = d2; p = 64; Kpad = 192; }
  else return;
  const int r = i / Kpad, j = i - r * Kpad;
  float v = 0.f;
  const int p3 = 3 * p;
  if (j < p3) {
    size_t base = (size_t)r * p;
    if (j < p)           v = x[base + j];
    else if (j < 2 * p)  v = m[base + j - p];
    else                 v = t[base + j - 2 * p];
  }
  dst[i] = f2bf(v);
}

// ---- phase-1: merged 3-group 128x128 GEMM (R3/R7 interior, proven) ------
__global__ __launch_bounds__(256)
void gemm128p1g(const ushort_t* __restrict__ A0, const ushort_t* __restrict__ A1,
                const ushort_t* __restrict__ A2,
                const ushort_t* __restrict__ B0w, const ushort_t* __restrict__ B1w,
                const ushort_t* __restrict__ B2w,
                const float* __restrict__ bias,
                ushort_t* __restrict__ hidden, float* __restrict__ outp,
                const int* __restrict__ i0, const int* __restrict__ i1,
                const int* __restrict__ i2) {
  __shared__ __align__(16) ushort_t lA[2][128 * 32];
  __shared__ __align__(16) ushort_t lB[2][128 * 32];
  const int t = threadIdx.x;
  const int wave = t >> 6, lane = t & 63;
  const int gm = blockIdx.x >> 6;             // group 0/1/2
  const int tm = (blockIdx.x & 63) * 128;     // within-group row tile
  const int tn = blockIdx.y * 128;
  const ushort_t* A = (gm == 0) ? A0 : (gm == 1) ? A1 : A2;
  const ushort_t* B = (gm == 0) ? B0w : (gm == 1) ? B1w : B2w;
  const int* idxg   = (gm == 0) ? i0 : (gm == 1) ? i1 : i2;
  const int Kpad    = (gm == 0) ? 64 : (gm == 1) ? 96 : 192;

  const int chunk = wave * 2;
  const int srow = chunk * 16 + (lane >> 2);
  const int scol = (((lane & 3) ^ ((lane >> 3) & 3)) * 8);
  const ushort_t* gA0 = A + (size_t)(tm + srow) * Kpad + scol;
  const ushort_t* gA1 = gA0 + (size_t)16 * Kpad;
  const ushort_t* gB0 = B + (size_t)(tn + srow) * Kpad + scol;
  const ushort_t* gB1 = gB0 + (size_t)16 * Kpad;
  const int ldsOff0 = chunk * 512;
  const int ldsOff1 = ldsOff0 + 512;

  const int wr = wave >> 1, wc = wave & 1;
  const f32x4 zero = {0.f, 0.f, 0.f, 0.f};
  f32x4 acc[4][4];
#pragma unroll
  for (int m2 = 0; m2 < 4; ++m2)
#pragma unroll
    for (int n2 = 0; n2 < 4; ++n2) acc[m2][n2] = zero;

  const int xf = ((lane & 15) >> 1) & 3;
  const int fcol = (((lane >> 4) ^ xf)) * 8;
  const int aoff = (wr * 64 + (lane & 15)) * 32 + fcol;
  const int boff = (wc * 64 + (lane & 15)) * 32 + fcol;

  const int nk = Kpad >> 5;
  gld_lds16(gA0, &lA[0][ldsOff0]); gld_lds16(gA1, &lA[0][ldsOff1]);
  gld_lds16(gB0, &lB[0][ldsOff0]); gld_lds16(gB1, &lB[0][ldsOff1]);
  gA0 += 32; gA1 += 32; gB0 += 32; gB1 += 32;

  for (int kk = 0; kk < nk; ++kk) {
    const int cur = kk & 1;
    if (kk + 1 < nk) {
      const int nxt = cur ^ 1;
      gld_lds16(gA0, &lA[nxt][ldsOff0]); gld_lds16(gA1, &lA[nxt][ldsOff1]);
      gld_lds16(gB0, &lB[nxt][ldsOff0]); gld_lds16(gB1, &lB[nxt][ldsOff1]);
      gA0 += 32; gA1 += 32; gB0 += 32; gB1 += 32;
      asm volatile("s_waitcnt vmcnt(4)" ::: "memory");
    } else {
      asm volatile("s_waitcnt vmcnt(0)" ::: "memory");
    }
    __builtin_amdgcn_s_barrier();
    asm volatile("" ::: "memory");

    const ushort_t* pa = &lA[cur][0] + aoff;
    const ushort_t* pb = &lB[cur][0] + boff;
    short8 aF[4], bF[4];
#pragma unroll
    for (int m2 = 0; m2 < 4; ++m2) aF[m2] = *(const short8*)(pa + m2 * 16 * 32);
#pragma unroll
    for (int n2 = 0; n2 < 4; ++n2) bF[n2] = *(const short8*)(pb + n2 * 16 * 32);
#pragma unroll
    for (int m2 = 0; m2 < 4; ++m2)
#pragma unroll
      for (int n2 = 0; n2 < 4; ++n2)
        acc[m2][n2] = __builtin_amdgcn_mfma_f32_16x16x32_bf16(
            aF[m2], bF[n2], acc[m2][n2], 0, 0, 0);
    __builtin_amdgcn_s_barrier();
    asm volatile("" ::: "memory");
  }

  const int layer = idxg[tm >> 9];
  const int rowBase = layer * N_TOK + (tm & (N_TOK - 1));

#pragma unroll
  for (int m2 = 0; m2 < 4; ++m2) {
#pragma unroll
    for (int n2 = 0; n2 < 4; ++n2) {
      const int colg = tn + wc * 64 + n2 * 16 + (lane & 15);
      const float bv = bias[colg];
#pragma unroll
      for (int r = 0; r < 4; ++r) {
        const int rowl = wr * 64 + m2 * 16 + (lane >> 4) * 4 + r;
        const float v = acc[m2][n2][r];
        const int grow = rowBase + rowl;
        if (colg < INTER) {
          float h = v + bv;
          h = h / (1.f + expf(-h));
          hidden[(size_t)grow * INTER + colg] = f2bf(h);
        } else {
          outp[(size_t)grow * EMBED + (colg - INTER)] = v + bv;
        }
      }
    }
  }
}

// ---- phase-2: 192x128 full-K GEMM, 32x32x16 MFMA ------------------------
// R10 structure byte-for-byte (2 blocks/CU, 80KB LDS, 4 waves 96x64 tile,
// same staging + XOR swizzle + minimal-barrier schedule + vmcnt(6) ledger),
// with the matrix op switched 16x16x32 -> 32x32x16 (m119: 2495 vs 2075 TF
// pipe rate, -17% MFMA cycles). Same 20 b128 frag reads per wave-KT.
// A frag (32x32x16): lane l holds A[row = base+mh*32+(l&31)]
//   [k = ks*16 + (l>>5)*8 .. +7]; chunk-in-row = (ks&1)*2 + (l>>5),
//   XOR'd with xl = ((l&31)>>1)&3 (stored swizzle). B symmetric.
// C/D (m74-verified): col = l&31, row = (r&3) + 8*(r>>2) + 4*(l>>5).
#define P2BUF 40960
#define P2BOFF 24576

__global__ __launch_bounds__(256, 2)
void gemm192x128(const ushort_t* __restrict__ A, const ushort_t* __restrict__ Bw,
                 const float* __restrict__ bias, float* __restrict__ outp) {
  __shared__ __align__(16) char smem[2 * P2BUF];
  const int tid = threadIdx.x;
  const int w = tid >> 6, l = tid & 63;

  const int L = blockIdx.x;
  const int xcd = L & 7, j = L >> 3;          // j in [0,128)
  const int nt = j & 7, mtl = j >> 3;         // nt fastest: A-slab reuse
  const int tm = (xcd * 16 + mtl) * 192, tn = nt * 128;

  // staging source pointers (pre-swizzled global, linear LDS dest) — R10
  const ushort_t* pA[6]; int dA[6];
#pragma unroll
  for (int jj = 0; jj < 6; ++jj) {
    const int q = w * 6 + jj;                 // 0..23
    const int ks = q / 12, rb = q % 12;
    const int row = rb * 16 + (l >> 2);
    const int c = (l & 3) ^ ((row >> 1) & 3);
    pA[jj] = A + (size_t)(tm + row) * 4096 + ks * 32 + c * 8;
    dA[jj] = ks * 12288 + rb * 1024;
  }
  const ushort_t* pB[4]; int dB[4];
#pragma unroll
  for (int jj = 0; jj < 4; ++jj) {
    const int q = w * 4 + jj;                 // 0..15
    const int ks = q >> 3, rb = q & 7;
    const int row = rb * 16 + (l >> 2);
    const int c = (l & 3) ^ ((row >> 1) & 3);
    pB[jj] = Bw + (size_t)(tn + row) * 4096 + ks * 32 + c * 8;
    dB[jj] = P2BOFF + ks * 8192 + rb * 1024;
  }

#define STGA6(BB) do { _Pragma("unroll") for (int jj = 0; jj < 6; ++jj) \
    gld_lds16(pA[jj], smem + (BB) + dA[jj]); \
    _Pragma("unroll") for (int jj = 0; jj < 6; ++jj) pA[jj] += 64; } while (0)
#define STGB4(BB) do { _Pragma("unroll") for (int jj = 0; jj < 4; ++jj) \
    gld_lds16(pB[jj], smem + (BB) + dB[jj]); \
    _Pragma("unroll") for (int jj = 0; jj < 4; ++jj) pB[jj] += 64; } while (0)

  // ---- 32x32x16 fragment addressing ----
  const int wr = w >> 1, wc = w & 1;          // 2M x 2N; wave tile 96x64
  const int xl32 = ((l & 31) >> 1) & 3;       // stored-swizzle XOR (lane const)
  const int rowA = (wr * 96 + (l & 31)) * 64; // byte base of A row
  const int rowB = (wc * 64 + (l & 31)) * 64; // byte base of B row
  int cks[4];                                  // chunk byte offset per ks16
#pragma unroll
  for (int ks = 0; ks < 4; ++ks)
    cks[ks] = ((((ks & 1) * 2 + (l >> 5)) ^ xl32)) * 16;

  f32x16 acc[3][2];
#pragma unroll
  for (int mh = 0; mh < 3; ++mh)
#pragma unroll
    for (int nh = 0; nh < 2; ++nh)
#pragma unroll
      for (int r = 0; r < 16; ++r) acc[mh][nh][r] = 0.f;
  short8 aF[3][4], bF[2][4];

#define LDA12(BB) do { _Pragma("unroll") for (int mh = 0; mh < 3; ++mh) { \
    _Pragma("unroll") for (int ks = 0; ks < 4; ++ks) \
      aF[mh][ks] = *(const short8*)(smem + (BB) + (ks >> 1) * 12288 + mh * 2048 + rowA + cks[ks]); } } while (0)
#define LDB8(BB) do { _Pragma("unroll") for (int nh = 0; nh < 2; ++nh) { \
    _Pragma("unroll") for (int ks = 0; ks < 4; ++ks) \
      bF[nh][ks] = *(const short8*)(smem + (BB) + P2BOFF + (ks >> 1) * 8192 + nh * 2048 + rowB + cks[ks]); } } while (0)
#define MF12(NH) do { _Pragma("unroll") for (int ks = 0; ks < 4; ++ks) { \
    _Pragma("unroll") for (int mh = 0; mh < 3; ++mh) \
      acc[mh][(NH)] = __builtin_amdgcn_mfma_f32_32x32x16_bf16( \
          aF[mh][ks], bF[(NH)][ks], acc[mh][(NH)], 0, 0, 0); } } while (0)
#define BARR do { __builtin_amdgcn_s_barrier(); asm volatile("" ::: "memory"); } while (0)
#define WAITV(N) do { asm volatile("s_waitcnt vmcnt(" #N ")" ::: "memory"); \
    __builtin_amdgcn_sched_barrier(0); } while (0)
#define PRIO1 __builtin_amdgcn_s_setprio(1)
#define PRIO0 __builtin_amdgcn_s_setprio(0)

  // prologue: A0,B0 -> buf0; A1 -> buf1; drain A0,B0 (leave A1 in flight)
  STGA6(0); STGB4(0);
  STGA6(P2BUF);
  WAITV(6);
  BARR;

  const int nit2 = 32;                         // 64 KTs, 2 per iteration
  for (int t2 = 0; t2 < nit2; ++t2) {
    const bool morA = (t2 + 1 < nit2);
    // ---- KT even (buf0) ----
    LDA12(0); LDB8(0);
    STGB4(P2BUF);                              // B(t+1) -> buf1
    PRIO1; MF12(0); PRIO0;                     // nh0: consumes ALL A reads
    BARR;                                      // seals buf0.A reads (all waves)
    if (morA) STGA6(0);                        // A(t+2) -> buf0
    PRIO1; MF12(1); PRIO0;                     // nh1 (bF from regs)
    if (morA) { WAITV(6); } else { WAITV(0); } // drain A(t+1)+B(t+1)
    BARR;
    // ---- KT odd (buf1) ----
    LDA12(P2BUF); LDB8(P2BUF);
    if (morA) STGB4(0);                        // B(t+2) -> buf0
    PRIO1; MF12(0); PRIO0;
    BARR;
    if (morA) STGA6(P2BUF);                    // A(t+3) -> buf1
    PRIO1; MF12(1); PRIO0;
    if (morA) { WAITV(6); } else { WAITV(0); }
    BARR;
  }

  // ---- epilogue: out += acc + bias (m74 C/D mapping, no atomics) ----
  float bv[2];
#pragma unroll
  for (int nh = 0; nh < 2; ++nh)
    bv[nh] = bias[tn + wc * 64 + nh * 32 + (l & 31)];
#pragma unroll
  for (int mh = 0; mh < 3; ++mh) {
    const int r0 = tm + wr * 96 + mh * 32 + 4 * (l >> 5);
#pragma unroll
    for (int nh = 0; nh < 2; ++nh) {
      const int col = tn + wc * 64 + nh * 32 + (l & 31);
#pragma unroll
      for (int rg = 0; rg < 4; ++rg) {
        float* po = outp + (size_t)(r0 + rg * 8) * EMBED + col;
#pragma unroll
        for (int rr = 0; rr < 4; ++rr)
          po[(size_t)rr * EMBED] += acc[mh][nh][rg * 4 + rr] + bv[nh];
      }
    }
  }
}

// ---- launch -------------------------------------------------------------

extern "C" void kernel_launch(void* const* d_in, const int* in_sizes, int n_in,
                              void* d_out, int out_size, void* d_ws, size_t ws_size,
                              hipStream_t stream) {
  const float* xg[3] = {(const float*)d_in[0], (const float*)d_in[3], (const float*)d_in[6]};
  const float* mg[3] = {(const float*)d_in[1], (const float*)d_in[4], (const float*)d_in[7]};
  const float* tg[3] = {(const float*)d_in[2], (const float*)d_in[5], (const float*)d_in[8]};
  const int* idxg[3] = {(const int*)d_in[9], (const int*)d_in[10], (const int*)d_in[11]};
  const float* W_lin = (const float*)d_in[12];
  const float* b_lin = (const float*)d_in[13];
  const float* W_res = (const float*)d_in[14];
  const float* b_res = (const float*)d_in[15];
  const float* W_out = (const float*)d_in[16];
  const float* b_out = (const float*)d_in[17];
  float* out = (float*)d_out;

  char* ws = (char*)d_ws;
  size_t off = 0;
  auto alloc = [&](size_t b) -> char* {
    size_t o = (off + 255) & ~(size_t)255;
    off = o + b;
    return ws + o;
  };

  ushort_t* hidden = (ushort_t*)alloc((size_t)MROWS * INTER * 2);   // 201 MB
  const int Kp[3] = {64, 96, 192};
  ushort_t* xsw[3];
  ushort_t* wcat[3];
  for (int g = 0; g < 3; ++g) xsw[g]  = (ushort_t*)alloc((size_t)8192 * Kp[g] * 2);
  for (int g = 0; g < 3; ++g) wcat[g] = (ushort_t*)alloc((size_t)NCAT * Kp[g] * 2);
  ushort_t* wout = (ushort_t*)alloc((size_t)EMBED * INTER * 2);     // 8 MB
  float* bcat = (float*)alloc((size_t)NCAT * 4);

  // merged preps: 2 dispatches
  const int wTotal = NCAT + EMBED * INTER + NCAT * 352;   // 6,001,664
  prep_w<<<(wTotal + 255) / 256, 256, 0, stream>>>(
      W_lin, W_res, W_out, b_lin, b_res, wout, wcat[0], wcat[1], wcat[2], bcat);
  const int xTotal = 8192 * 352;                          // 2,883,584
  prep_x<<<(xTotal + 255) / 256, 256, 0, stream>>>(
      xg[0], mg[0], tg[0], xg[1], mg[1], tg[1], xg[2], mg[2], tg[2],
      xsw[0], xsw[1], xsw[2]);

  // phase 1: all 3 groups in ONE dispatch: [8192 x Kp] @ [5120 x Kp]^T each
  gemm128p1g<<<dim3(192, 40), 256, 0, stream>>>(
      xsw[0], xsw[1], xsw[2], wcat[0], wcat[1], wcat[2], bcat,
      hidden, out, idxg[0], idxg[1], idxg[2]);
  // phase 2: [24576 x 4096] @ [1024 x 4096]^T, full K, out += acc + b_out
  gemm192x128<<<dim3(1024), 256, 0, stream>>>(hidden, wout, b_out, out);
}

// Round 15
// 391.743 us; speedup vs baseline: 5.2571x; 1.0016x over previous
//
#include <hip/hip_runtime.h>
#include <hip/hip_bf16.h>
#include <math.h>

typedef unsigned short ushort_t;
typedef short short8 __attribute__((ext_vector_type(8)));
typedef float f32x4 __attribute__((ext_vector_type(4)));
typedef float f32x16 __attribute__((ext_vector_type(16)));

#define N_TOK 512
#define EMBED 1024
#define INTER 4096
#define NCAT  5120   /* INTER + EMBED */
#define MROWS 24576  /* 48 * 512 */

__device__ __forceinline__ ushort_t f2bf(float f) {
  union { float f; unsigned int u; } c; c.f = f;
  unsigned int u = c.u;
  unsigned int r = u + 0x7fffu + ((u >> 16) & 1u);
  return (ushort_t)(r >> 16);
}

__device__ __forceinline__ void gld_lds16(const void* g, void* l) {
  __builtin_amdgcn_global_load_lds(
      (const __attribute__((address_space(1))) void*)g,
      (__attribute__((address_space(3))) void*)l, 16, 0, 0);
}

// ---- merged prep kernels ------------------------------------------------
__global__ void prep_w(const float* __restrict__ Wl, const float* __restrict__ Wr,
                       const float* __restrict__ Wo,
                       const float* __restrict__ bl, const float* __restrict__ br,
                       ushort_t* __restrict__ wout,
                       ushort_t* __restrict__ w0, ushort_t* __restrict__ w1,
                       ushort_t* __restrict__ w2, float* __restrict__ bcat) {
  int i = blockIdx.x * 256 + threadIdx.x;
  if (i < NCAT) { bcat[i] = (i < INTER) ? bl[i] : br[i - INTER]; return; }
  i -= NCAT;
  if (i < EMBED * INTER) { wout[i] = f2bf(Wo[i]); return; }
  i -= EMBED * INTER;
  ushort_t* dst; int Kpad, P3;
  if (i < NCAT * 64)            { dst = w0; Kpad = 64;  P3 = 48; }
  else if (i < NCAT * 160)      { i -= NCAT * 64;  dst = w1; Kpad = 96;  P3 = 96; }
  else if (i < NCAT * 352)      { i -= NCAT * 160; dst = w2; Kpad = 192; P3 = 192; }
  else return;
  const int r = i / Kpad, j = i - r * Kpad;
  float v = 0.f;
  if (j < P3) {
    float scale = 96.0f / (float)P3;
    float src = (j + 0.5f) * scale - 0.5f;
    src = fminf(fmaxf(src, 0.0f), 95.0f);
    int i0 = (int)src;
    int i1 = min(i0 + 1, 95);
    float tt = src - (float)i0;
    const float* Wrow = (r < INTER) ? (Wl + (size_t)r * 96)
                                    : (Wr + (size_t)(r - INTER) * 96);
    v = Wrow[i0] * (1.f - tt) + Wrow[i1] * tt;
  }
  dst[i] = f2bf(v);
}

__global__ void prep_x(const float* __restrict__ x0, const float* __restrict__ m0,
                       const float* __restrict__ t0,
                       const float* __restrict__ x1, const float* __restrict__ m1,
                       const float* __restrict__ t1,
                       const float* __restrict__ x2, const float* __restrict__ m2,
                       const float* __restrict__ t2,
                       ushort_t* __restrict__ d0, ushort_t* __restrict__ d1,
                       ushort_t* __restrict__ d2) {
  int i = blockIdx.x * 256 + threadIdx.x;
  const float *x, *m, *t; ushort_t* dst; int p, Kpad;
  if (i < 8192 * 64)            { x = x0; m = m0; t = t0; dst = d0; p = 16; Kpad = 64; }
  else if (i < 8192 * 160)      { i -= 8192 * 64;  x = x1; m = m1; t = t1; dst = d1; p = 32; Kpad = 96; }
  else if (i < 8192 * 352)      { i -= 8192 * 160; x = x2; m = m2; t = t2; dst = d2; p = 64; Kpad = 192; }
  else return;
  const int r = i / Kpad, j = i - r * Kpad;
  float v = 0.f;
  const int p3 = 3 * p;
  if (j < p3) {
    size_t base = (size_t)r * p;
    if (j < p)           v = x[base + j];
    else if (j < 2 * p)  v = m[base + j - p];
    else                 v = t[base + j - 2 * p];
  }
  dst[i] = f2bf(v);
}

// ---- phase-1: merged 3-group 128x128 GEMM (R3/R7 interior, proven) ------
__global__ __launch_bounds__(256)
void gemm128p1g(const ushort_t* __restrict__ A0, const ushort_t* __restrict__ A1,
                const ushort_t* __restrict__ A2,
                const ushort_t* __restrict__ B0w, const ushort_t* __restrict__ B1w,
                const ushort_t* __restrict__ B2w,
                const float* __restrict__ bias,
                ushort_t* __restrict__ hidden, float* __restrict__ outp,
                const int* __restrict__ i0, const int* __restrict__ i1,
                const int* __restrict__ i2) {
  __shared__ __align__(16) ushort_t lA[2][128 * 32];
  __shared__ __align__(16) ushort_t lB[2][128 * 32];
  const int t = threadIdx.x;
  const int wave = t >> 6, lane = t & 63;
  const int gm = blockIdx.x >> 6;             // group 0/1/2
  const int tm = (blockIdx.x & 63) * 128;     // within-group row tile
  const int tn = blockIdx.y * 128;
  const ushort_t* A = (gm == 0) ? A0 : (gm == 1) ? A1 : A2;
  const ushort_t* B = (gm == 0) ? B0w : (gm == 1) ? B1w : B2w;
  const int* idxg   = (gm == 0) ? i0 : (gm == 1) ? i1 : i2;
  const int Kpad    = (gm == 0) ? 64 : (gm == 1) ? 96 : 192;

  const int chunk = wave * 2;
  const int srow = chunk * 16 + (lane >> 2);
  const int scol = (((lane & 3) ^ ((lane >> 3) & 3)) * 8);
  const ushort_t* gA0 = A + (size_t)(tm + srow) * Kpad + scol;
  const ushort_t* gA1 = gA0 + (size_t)16 * Kpad;
  const ushort_t* gB0 = B + (size_t)(tn + srow) * Kpad + scol;
  const ushort_t* gB1 = gB0 + (size_t)16 * Kpad;
  const int ldsOff0 = chunk * 512;
  const int ldsOff1 = ldsOff0 + 512;

  const int wr = wave >> 1, wc = wave & 1;
  const f32x4 zero = {0.f, 0.f, 0.f, 0.f};
  f32x4 acc[4][4];
#pragma unroll
  for (int m2 = 0; m2 < 4; ++m2)
#pragma unroll
    for (int n2 = 0; n2 < 4; ++n2) acc[m2][n2] = zero;

  const int xf = ((lane & 15) >> 1) & 3;
  const int fcol = (((lane >> 4) ^ xf)) * 8;
  const int aoff = (wr * 64 + (lane & 15)) * 32 + fcol;
  const int boff = (wc * 64 + (lane & 15)) * 32 + fcol;

  const int nk = Kpad >> 5;
  gld_lds16(gA0, &lA[0][ldsOff0]); gld_lds16(gA1, &lA[0][ldsOff1]);
  gld_lds16(gB0, &lB[0][ldsOff0]); gld_lds16(gB1, &lB[0][ldsOff1]);
  gA0 += 32; gA1 += 32; gB0 += 32; gB1 += 32;

  for (int kk = 0; kk < nk; ++kk) {
    const int cur = kk & 1;
    if (kk + 1 < nk) {
      const int nxt = cur ^ 1;
      gld_lds16(gA0, &lA[nxt][ldsOff0]); gld_lds16(gA1, &lA[nxt][ldsOff1]);
      gld_lds16(gB0, &lB[nxt][ldsOff0]); gld_lds16(gB1, &lB[nxt][ldsOff1]);
      gA0 += 32; gA1 += 32; gB0 += 32; gB1 += 32;
      asm volatile("s_waitcnt vmcnt(4)" ::: "memory");
    } else {
      asm volatile("s_waitcnt vmcnt(0)" ::: "memory");
    }
    __builtin_amdgcn_s_barrier();
    asm volatile("" ::: "memory");

    const ushort_t* pa = &lA[cur][0] + aoff;
    const ushort_t* pb = &lB[cur][0] + boff;
    short8 aF[4], bF[4];
#pragma unroll
    for (int m2 = 0; m2 < 4; ++m2) aF[m2] = *(const short8*)(pa + m2 * 16 * 32);
#pragma unroll
    for (int n2 = 0; n2 < 4; ++n2) bF[n2] = *(const short8*)(pb + n2 * 16 * 32);
#pragma unroll
    for (int m2 = 0; m2 < 4; ++m2)
#pragma unroll
      for (int n2 = 0; n2 < 4; ++n2)
        acc[m2][n2] = __builtin_amdgcn_mfma_f32_16x16x32_bf16(
            aF[m2], bF[n2], acc[m2][n2], 0, 0, 0);
    __builtin_amdgcn_s_barrier();
    asm volatile("" ::: "memory");
  }

  const int layer = idxg[tm >> 9];
  const int rowBase = layer * N_TOK + (tm & (N_TOK - 1));

#pragma unroll
  for (int m2 = 0; m2 < 4; ++m2) {
#pragma unroll
    for (int n2 = 0; n2 < 4; ++n2) {
      const int colg = tn + wc * 64 + n2 * 16 + (lane & 15);
      const float bv = bias[colg];
#pragma unroll
      for (int r = 0; r < 4; ++r) {
        const int rowl = wr * 64 + m2 * 16 + (lane >> 4) * 4 + r;
        const float v = acc[m2][n2][r];
        const int grow = rowBase + rowl;
        if (colg < INTER) {
          float h = v + bv;
          h = h / (1.f + expf(-h));
          hidden[(size_t)grow * INTER + colg] = f2bf(h);
        } else {
          outp[(size_t)grow * EMBED + (colg - INTER)] = v + bv;
        }
      }
    }
  }
}

// ---- phase-2: 192x128 full-K GEMM, 32x32x16 MFMA, fixed swizzle --------
// R14 with the bank-conflict bug fixed: the stored-chunk swizzle gains a
// ((row>>3)&3) term so 32-row fragment reads hit 8 distinct 16B bank
// slots with 4 lanes each (the conflict-free schedule for a 4-cycle b128
// wave read). Invariant: LDS (row,pos) holds global chunk pos ^ S(row),
// S(row) = ((row>>1)&3) ^ ((row>>3)&3), applied identically at stage
// (source addr) and read (rule 21). Read-side S is per-lane constant
// since all row bases are multiples of 32.
// Everything else identical to R10/R14: 2 blocks/CU, 80KB LDS, 4 waves
// 96x64 tile, minimal-barrier schedule, vmcnt(6) ledger.
#define P2BUF 40960
#define P2BOFF 24576

__global__ __launch_bounds__(256, 2)
void gemm192x128(const ushort_t* __restrict__ A, const ushort_t* __restrict__ Bw,
                 const float* __restrict__ bias, float* __restrict__ outp) {
  __shared__ __align__(16) char smem[2 * P2BUF];
  const int tid = threadIdx.x;
  const int w = tid >> 6, l = tid & 63;

  const int L = blockIdx.x;
  const int xcd = L & 7, j = L >> 3;          // j in [0,128)
  const int nt = j & 7, mtl = j >> 3;         // nt fastest: A-slab reuse
  const int tm = (xcd * 16 + mtl) * 192, tn = nt * 128;

  // staging source pointers (pre-swizzled global, linear LDS dest)
  const ushort_t* pA[6]; int dA[6];
#pragma unroll
  for (int jj = 0; jj < 6; ++jj) {
    const int q = w * 6 + jj;                 // 0..23
    const int ks = q / 12, rb = q % 12;
    const int row = rb * 16 + (l >> 2);
    const int c = (l & 3) ^ ((row >> 1) & 3) ^ ((row >> 3) & 3);
    pA[jj] = A + (size_t)(tm + row) * 4096 + ks * 32 + c * 8;
    dA[jj] = ks * 12288 + rb * 1024;
  }
  const ushort_t* pB[4]; int dB[4];
#pragma unroll
  for (int jj = 0; jj < 4; ++jj) {
    const int q = w * 4 + jj;                 // 0..15
    const int ks = q >> 3, rb = q & 7;
    const int row = rb * 16 + (l >> 2);
    const int c = (l & 3) ^ ((row >> 1) & 3) ^ ((row >> 3) & 3);
    pB[jj] = Bw + (size_t)(tn + row) * 4096 + ks * 32 + c * 8;
    dB[jj] = P2BOFF + ks * 8192 + rb * 1024;
  }

#define STGA6(BB) do { _Pragma("unroll") for (int jj = 0; jj < 6; ++jj) \
    gld_lds16(pA[jj], smem + (BB) + dA[jj]); \
    _Pragma("unroll") for (int jj = 0; jj < 6; ++jj) pA[jj] += 64; } while (0)
#define STGB4(BB) do { _Pragma("unroll") for (int jj = 0; jj < 4; ++jj) \
    gld_lds16(pB[jj], smem + (BB) + dB[jj]); \
    _Pragma("unroll") for (int jj = 0; jj < 4; ++jj) pB[jj] += 64; } while (0)

  // ---- 32x32x16 fragment addressing (fixed swizzle) ----
  const int wr = w >> 1, wc = w & 1;          // 2M x 2N; wave tile 96x64
  const int sl = (((l & 31) >> 1) & 3) ^ (((l & 31) >> 3) & 3); // S(row), lane-const
  const int rowA = (wr * 96 + (l & 31)) * 64; // byte base of A row
  const int rowB = (wc * 64 + (l & 31)) * 64; // byte base of B row
  int cks[4];                                  // chunk byte offset per ks16
#pragma unroll
  for (int ks = 0; ks < 4; ++ks)
    cks[ks] = ((((ks & 1) * 2 + (l >> 5)) ^ sl)) * 16;

  f32x16 acc[3][2];
#pragma unroll
  for (int mh = 0; mh < 3; ++mh)
#pragma unroll
    for (int nh = 0; nh < 2; ++nh)
#pragma unroll
      for (int r = 0; r < 16; ++r) acc[mh][nh][r] = 0.f;
  short8 aF[3][4], bF[2][4];

#define LDA12(BB) do { _Pragma("unroll") for (int mh = 0; mh < 3; ++mh) { \
    _Pragma("unroll") for (int ks = 0; ks < 4; ++ks) \
      aF[mh][ks] = *(const short8*)(smem + (BB) + (ks >> 1) * 12288 + mh * 2048 + rowA + cks[ks]); } } while (0)
#define LDB8(BB) do { _Pragma("unroll") for (int nh = 0; nh < 2; ++nh) { \
    _Pragma("unroll") for (int ks = 0; ks < 4; ++ks) \
      bF[nh][ks] = *(const short8*)(smem + (BB) + P2BOFF + (ks >> 1) * 8192 + nh * 2048 + rowB + cks[ks]); } } while (0)
#define MF12(NH) do { _Pragma("unroll") for (int ks = 0; ks < 4; ++ks) { \
    _Pragma("unroll") for (int mh = 0; mh < 3; ++mh) \
      acc[mh][(NH)] = __builtin_amdgcn_mfma_f32_32x32x16_bf16( \
          aF[mh][ks], bF[(NH)][ks], acc[mh][(NH)], 0, 0, 0); } } while (0)
#define BARR do { __builtin_amdgcn_s_barrier(); asm volatile("" ::: "memory"); } while (0)
#define WAITV(N) do { asm volatile("s_waitcnt vmcnt(" #N ")" ::: "memory"); \
    __builtin_amdgcn_sched_barrier(0); } while (0)
#define PRIO1 __builtin_amdgcn_s_setprio(1)
#define PRIO0 __builtin_amdgcn_s_setprio(0)

  // prologue: A0,B0 -> buf0; A1 -> buf1; drain A0,B0 (leave A1 in flight)
  STGA6(0); STGB4(0);
  STGA6(P2BUF);
  WAITV(6);
  BARR;

  const int nit2 = 32;                         // 64 KTs, 2 per iteration
  for (int t2 = 0; t2 < nit2; ++t2) {
    const bool morA = (t2 + 1 < nit2);
    // ---- KT even (buf0) ----
    LDA12(0); LDB8(0);
    STGB4(P2BUF);                              // B(t+1) -> buf1
    PRIO1; MF12(0); PRIO0;                     // nh0: consumes ALL A reads
    BARR;                                      // seals buf0.A reads (all waves)
    if (morA) STGA6(0);                        // A(t+2) -> buf0
    PRIO1; MF12(1); PRIO0;                     // nh1 (bF from regs)
    if (morA) { WAITV(6); } else { WAITV(0); } // drain A(t+1)+B(t+1)
    BARR;
    // ---- KT odd (buf1) ----
    LDA12(P2BUF); LDB8(P2BUF);
    if (morA) STGB4(0);                        // B(t+2) -> buf0
    PRIO1; MF12(0); PRIO0;
    BARR;
    if (morA) STGA6(P2BUF);                    // A(t+3) -> buf1
    PRIO1; MF12(1); PRIO0;
    if (morA) { WAITV(6); } else { WAITV(0); }
    BARR;
  }

  // ---- epilogue: out += acc + bias (m74 C/D mapping, no atomics) ----
  float bv[2];
#pragma unroll
  for (int nh = 0; nh < 2; ++nh)
    bv[nh] = bias[tn + wc * 64 + nh * 32 + (l & 31)];
#pragma unroll
  for (int mh = 0; mh < 3; ++mh) {
    const int r0 = tm + wr * 96 + mh * 32 + 4 * (l >> 5);
#pragma unroll
    for (int nh = 0; nh < 2; ++nh) {
      const int col = tn + wc * 64 + nh * 32 + (l & 31);
#pragma unroll
      for (int rg = 0; rg < 4; ++rg) {
        float* po = outp + (size_t)(r0 + rg * 8) * EMBED + col;
#pragma unroll
        for (int rr = 0; rr < 4; ++rr)
          po[(size_t)rr * EMBED] += acc[mh][nh][rg * 4 + rr] + bv[nh];
      }
    }
  }
}

// ---- launch -------------------------------------------------------------

extern "C" void kernel_launch(void* const* d_in, const int* in_sizes, int n_in,
                              void* d_out, int out_size, void* d_ws, size_t ws_size,
                              hipStream_t stream) {
  const float* xg[3] = {(const float*)d_in[0], (const float*)d_in[3], (const float*)d_in[6]};
  const float* mg[3] = {(const float*)d_in[1], (const float*)d_in[4], (const float*)d_in[7]};
  const float* tg[3] = {(const float*)d_in[2], (const float*)d_in[5], (const float*)d_in[8]};
  const int* idxg[3] = {(const int*)d_in[9], (const int*)d_in[10], (const int*)d_in[11]};
  const float* W_lin = (const float*)d_in[12];
  const float* b_lin = (const float*)d_in[13];
  const float* W_res = (const float*)d_in[14];
  const float* b_res = (const float*)d_in[15];
  const float* W_out = (const float*)d_in[16];
  const float* b_out = (const float*)d_in[17];
  float* out = (float*)d_out;

  char* ws = (char*)d_ws;
  size_t off = 0;
  auto alloc = [&](size_t b) -> char* {
    size_t o = (off + 255) & ~(size_t)255;
    off = o + b;
    return ws + o;
  };

  ushort_t* hidden = (ushort_t*)alloc((size_t)MROWS * INTER * 2);   // 201 MB
  const int Kp[3] = {64, 96, 192};
  ushort_t* xsw[3];
  ushort_t* wcat[3];
  for (int g = 0; g < 3; ++g) xsw[g]  = (ushort_t*)alloc((size_t)8192 * Kp[g] * 2);
  for (int g = 0; g < 3; ++g) wcat[g] = (ushort_t*)alloc((size_t)NCAT * Kp[g] * 2);
  ushort_t* wout = (ushort_t*)alloc((size_t)EMBED * INTER * 2);     // 8 MB
  float* bcat = (float*)alloc((size_t)NCAT * 4);

  // merged preps: 2 dispatches
  const int wTotal = NCAT + EMBED * INTER + NCAT * 352;   // 6,001,664
  prep_w<<<(wTotal + 255) / 256, 256, 0, stream>>>(
      W_lin, W_res, W_out, b_lin, b_res, wout, wcat[0], wcat[1], wcat[2], bcat);
  const int xTotal = 8192 * 352;                          // 2,883,584
  prep_x<<<(xTotal + 255) / 256, 256, 0, stream>>>(
      xg[0], mg[0], tg[0], xg[1], mg[1], tg[1], xg[2], mg[2], tg[2],
      xsw[0], xsw[1], xsw[2]);

  // phase 1: all 3 groups in ONE dispatch: [8192 x Kp] @ [5120 x Kp]^T each
  gemm128p1g<<<dim3(192, 40), 256, 0, stream>>>(
      xsw[0], xsw[1], xsw[2], wcat[0], wcat[1], wcat[2], bcat,
      hidden, out, idxg[0], idxg[1], idxg[2]);
  // phase 2: [24576 x 4096] @ [1024 x 4096]^T, full K, out += acc + b_out
  gemm192x128<<<dim3(1024), 256, 0, stream>>>(hidden, wout, b_out, out);
}

// Round 16
// 388.044 us; speedup vs baseline: 5.3072x; 1.0095x over previous
//
#include <hip/hip_runtime.h>
#include <hip/hip_bf16.h>
#include <math.h>

typedef unsigned short ushort_t;
typedef short short8 __attribute__((ext_vector_type(8)));
typedef float f32x4 __attribute__((ext_vector_type(4)));
typedef float f32x16 __attribute__((ext_vector_type(16)));

#define N_TOK 512
#define EMBED 1024
#define INTER 4096
#define NCAT  5120   /* INTER + EMBED */
#define MROWS 24576  /* 48 * 512 */

__device__ __forceinline__ ushort_t f2bf(float f) {
  union { float f; unsigned int u; } c; c.f = f;
  unsigned int u = c.u;
  unsigned int r = u + 0x7fffu + ((u >> 16) & 1u);
  return (ushort_t)(r >> 16);
}

__device__ __forceinline__ void gld_lds16(const void* g, void* l) {
  __builtin_amdgcn_global_load_lds(
      (const __attribute__((address_space(1))) void*)g,
      (__attribute__((address_space(3))) void*)l, 16, 0, 0);
}

// ---- merged prep kernels ------------------------------------------------
__global__ void prep_w(const float* __restrict__ Wl, const float* __restrict__ Wr,
                       const float* __restrict__ Wo,
                       const float* __restrict__ bl, const float* __restrict__ br,
                       ushort_t* __restrict__ wout,
                       ushort_t* __restrict__ w0, ushort_t* __restrict__ w1,
                       ushort_t* __restrict__ w2, float* __restrict__ bcat) {
  int i = blockIdx.x * 256 + threadIdx.x;
  if (i < NCAT) { bcat[i] = (i < INTER) ? bl[i] : br[i - INTER]; return; }
  i -= NCAT;
  if (i < EMBED * INTER) { wout[i] = f2bf(Wo[i]); return; }
  i -= EMBED * INTER;
  ushort_t* dst; int Kpad, P3;
  if (i < NCAT * 64)            { dst = w0; Kpad = 64;  P3 = 48; }
  else if (i < NCAT * 160)      { i -= NCAT * 64;  dst = w1; Kpad = 96;  P3 = 96; }
  else if (i < NCAT * 352)      { i -= NCAT * 160; dst = w2; Kpad = 192; P3 = 192; }
  else return;
  const int r = i / Kpad, j = i - r * Kpad;
  float v = 0.f;
  if (j < P3) {
    float scale = 96.0f / (float)P3;
    float src = (j + 0.5f) * scale - 0.5f;
    src = fminf(fmaxf(src, 0.0f), 95.0f);
    int i0 = (int)src;
    int i1 = min(i0 + 1, 95);
    float tt = src - (float)i0;
    const float* Wrow = (r < INTER) ? (Wl + (size_t)r * 96)
                                    : (Wr + (size_t)(r - INTER) * 96);
    v = Wrow[i0] * (1.f - tt) + Wrow[i1] * tt;
  }
  dst[i] = f2bf(v);
}

__global__ void prep_x(const float* __restrict__ x0, const float* __restrict__ m0,
                       const float* __restrict__ t0,
                       const float* __restrict__ x1, const float* __restrict__ m1,
                       const float* __restrict__ t1,
                       const float* __restrict__ x2, const float* __restrict__ m2,
                       const float* __restrict__ t2,
                       ushort_t* __restrict__ d0, ushort_t* __restrict__ d1,
                       ushort_t* __restrict__ d2) {
  int i = blockIdx.x * 256 + threadIdx.x;
  const float *x, *m, *t; ushort_t* dst; int p, Kpad;
  if (i < 8192 * 64)            { x = x0; m = m0; t = t0; dst = d0; p = 16; Kpad = 64; }
  else if (i < 8192 * 160)      { i -= 8192 * 64;  x = x1; m = m1; t = t1; dst = d1; p = 32; Kpad = 96; }
  else if (i < 8192 * 352)      { i -= 8192 * 160; x = x2; m = m2; t = t2; dst = d2; p = 64; Kpad = 192; }
  else return;
  const int r = i / Kpad, j = i - r * Kpad;
  float v = 0.f;
  const int p3 = 3 * p;
  if (j < p3) {
    size_t base = (size_t)r * p;
    if (j < p)           v = x[base + j];
    else if (j < 2 * p)  v = m[base + j - p];
    else                 v = t[base + j - 2 * p];
  }
  dst[i] = f2bf(v);
}

// ---- phase-1: merged 3-group 128x128 GEMM (R3/R7 interior, proven) ------
__global__ __launch_bounds__(256)
void gemm128p1g(const ushort_t* __restrict__ A0, const ushort_t* __restrict__ A1,
                const ushort_t* __restrict__ A2,
                const ushort_t* __restrict__ B0w, const ushort_t* __restrict__ B1w,
                const ushort_t* __restrict__ B2w,
                const float* __restrict__ bias,
                ushort_t* __restrict__ hidden, float* __restrict__ outp,
                const int* __restrict__ i0, const int* __restrict__ i1,
                const int* __restrict__ i2) {
  __shared__ __align__(16) ushort_t lA[2][128 * 32];
  __shared__ __align__(16) ushort_t lB[2][128 * 32];
  const int t = threadIdx.x;
  const int wave = t >> 6, lane = t & 63;
  const int gm = blockIdx.x >> 6;             // group 0/1/2
  const int tm = (blockIdx.x & 63) * 128;     // within-group row tile
  const int tn = blockIdx.y * 128;
  const ushort_t* A = (gm == 0) ? A0 : (gm == 1) ? A1 : A2;
  const ushort_t* B = (gm == 0) ? B0w : (gm == 1) ? B1w : B2w;
  const int* idxg   = (gm == 0) ? i0 : (gm == 1) ? i1 : i2;
  const int Kpad    = (gm == 0) ? 64 : (gm == 1) ? 96 : 192;

  const int chunk = wave * 2;
  const int srow = chunk * 16 + (lane >> 2);
  const int scol = (((lane & 3) ^ ((lane >> 3) & 3)) * 8);
  const ushort_t* gA0 = A + (size_t)(tm + srow) * Kpad + scol;
  const ushort_t* gA1 = gA0 + (size_t)16 * Kpad;
  const ushort_t* gB0 = B + (size_t)(tn + srow) * Kpad + scol;
  const ushort_t* gB1 = gB0 + (size_t)16 * Kpad;
  const int ldsOff0 = chunk * 512;
  const int ldsOff1 = ldsOff0 + 512;

  const int wr = wave >> 1, wc = wave & 1;
  const f32x4 zero = {0.f, 0.f, 0.f, 0.f};
  f32x4 acc[4][4];
#pragma unroll
  for (int m2 = 0; m2 < 4; ++m2)
#pragma unroll
    for (int n2 = 0; n2 < 4; ++n2) acc[m2][n2] = zero;

  const int xf = ((lane & 15) >> 1) & 3;
  const int fcol = (((lane >> 4) ^ xf)) * 8;
  const int aoff = (wr * 64 + (lane & 15)) * 32 + fcol;
  const int boff = (wc * 64 + (lane & 15)) * 32 + fcol;

  const int nk = Kpad >> 5;
  gld_lds16(gA0, &lA[0][ldsOff0]); gld_lds16(gA1, &lA[0][ldsOff1]);
  gld_lds16(gB0, &lB[0][ldsOff0]); gld_lds16(gB1, &lB[0][ldsOff1]);
  gA0 += 32; gA1 += 32; gB0 += 32; gB1 += 32;

  for (int kk = 0; kk < nk; ++kk) {
    const int cur = kk & 1;
    if (kk + 1 < nk) {
      const int nxt = cur ^ 1;
      gld_lds16(gA0, &lA[nxt][ldsOff0]); gld_lds16(gA1, &lA[nxt][ldsOff1]);
      gld_lds16(gB0, &lB[nxt][ldsOff0]); gld_lds16(gB1, &lB[nxt][ldsOff1]);
      gA0 += 32; gA1 += 32; gB0 += 32; gB1 += 32;
      asm volatile("s_waitcnt vmcnt(4)" ::: "memory");
    } else {
      asm volatile("s_waitcnt vmcnt(0)" ::: "memory");
    }
    __builtin_amdgcn_s_barrier();
    asm volatile("" ::: "memory");

    const ushort_t* pa = &lA[cur][0] + aoff;
    const ushort_t* pb = &lB[cur][0] + boff;
    short8 aF[4], bF[4];
#pragma unroll
    for (int m2 = 0; m2 < 4; ++m2) aF[m2] = *(const short8*)(pa + m2 * 16 * 32);
#pragma unroll
    for (int n2 = 0; n2 < 4; ++n2) bF[n2] = *(const short8*)(pb + n2 * 16 * 32);
#pragma unroll
    for (int m2 = 0; m2 < 4; ++m2)
#pragma unroll
      for (int n2 = 0; n2 < 4; ++n2)
        acc[m2][n2] = __builtin_amdgcn_mfma_f32_16x16x32_bf16(
            aF[m2], bF[n2], acc[m2][n2], 0, 0, 0);
    __builtin_amdgcn_s_barrier();
    asm volatile("" ::: "memory");
  }

  const int layer = idxg[tm >> 9];
  const int rowBase = layer * N_TOK + (tm & (N_TOK - 1));

#pragma unroll
  for (int m2 = 0; m2 < 4; ++m2) {
#pragma unroll
    for (int n2 = 0; n2 < 4; ++n2) {
      const int colg = tn + wc * 64 + n2 * 16 + (lane & 15);
      const float bv = bias[colg];
#pragma unroll
      for (int r = 0; r < 4; ++r) {
        const int rowl = wr * 64 + m2 * 16 + (lane >> 4) * 4 + r;
        const float v = acc[m2][n2][r];
        const int grow = rowBase + rowl;
        if (colg < INTER) {
          float h = v + bv;
          h = h / (1.f + expf(-h));
          hidden[(size_t)grow * INTER + colg] = f2bf(h);
        } else {
          outp[(size_t)grow * EMBED + (colg - INTER)] = v + bv;
        }
      }
    }
  }
}

// ---- phase-2: 192x128 full-K GEMM, 32x32x16 MFMA, sigma-swizzle --------
// Conflict model (from R10=0 / R14,R15=2.097e7-identical): b128 reads are
// serviced as 8 quad-pair groups G_j = {4j..4j+3} U {32+4j..32+4j+3},
// spanning rows 4j..4j+3 only. Storage invariant: LDS (row, pos) holds
// logical chunk sigma(pos ^ S(row)), sigma = 2-bit bit-reverse
// (0<->0, 1<->2, 3<->3), S(r) = (r>>1)&3.
// Read: pos = sigma(c) ^ S; with c = (ks&1)*2 + (l>>5), sigma(c) =
// (l>>5)*2 + (ks&1) (pure index swap). Within each G_j the 8 accesses
// cover all 8 bank-quartets exactly once (i in {0,2} -> slots 0-3,
// i in {1,3} -> slots 4-7) for both ks parities -> conflict-free.
// Staging: position (l&3) sources chunk sigma((l&3) ^ S(row)) — a per-quad
// permutation of the same 64B row (coalescing preserved; rule 21).
// Everything else identical to R10/R14/R15.
#define P2BUF 40960
#define P2BOFF 24576

__global__ __launch_bounds__(256, 2)
void gemm192x128(const ushort_t* __restrict__ A, const ushort_t* __restrict__ Bw,
                 const float* __restrict__ bias, float* __restrict__ outp) {
  __shared__ __align__(16) char smem[2 * P2BUF];
  const int tid = threadIdx.x;
  const int w = tid >> 6, l = tid & 63;

  const int L = blockIdx.x;
  const int xcd = L & 7, j = L >> 3;          // j in [0,128)
  const int nt = j & 7, mtl = j >> 3;         // nt fastest: A-slab reuse
  const int tm = (xcd * 16 + mtl) * 192, tn = nt * 128;

  // staging source pointers (pre-swizzled global, linear LDS dest)
  const ushort_t* pA[6]; int dA[6];
#pragma unroll
  for (int jj = 0; jj < 6; ++jj) {
    const int q = w * 6 + jj;                 // 0..23
    const int ks = q / 12, rb = q % 12;
    const int row = rb * 16 + (l >> 2);
    const int ps = (l & 3) ^ ((row >> 1) & 3);
    const int c = ((ps & 1) << 1) | ((ps >> 1) & 1);   // sigma(ps)
    pA[jj] = A + (size_t)(tm + row) * 4096 + ks * 32 + c * 8;
    dA[jj] = ks * 12288 + rb * 1024;
  }
  const ushort_t* pB[4]; int dB[4];
#pragma unroll
  for (int jj = 0; jj < 4; ++jj) {
    const int q = w * 4 + jj;                 // 0..15
    const int ks = q >> 3, rb = q & 7;
    const int row = rb * 16 + (l >> 2);
    const int ps = (l & 3) ^ ((row >> 1) & 3);
    const int c = ((ps & 1) << 1) | ((ps >> 1) & 1);   // sigma(ps)
    pB[jj] = Bw + (size_t)(tn + row) * 4096 + ks * 32 + c * 8;
    dB[jj] = P2BOFF + ks * 8192 + rb * 1024;
  }

#define STGA6(BB) do { _Pragma("unroll") for (int jj = 0; jj < 6; ++jj) \
    gld_lds16(pA[jj], smem + (BB) + dA[jj]); \
    _Pragma("unroll") for (int jj = 0; jj < 6; ++jj) pA[jj] += 64; } while (0)
#define STGB4(BB) do { _Pragma("unroll") for (int jj = 0; jj < 4; ++jj) \
    gld_lds16(pB[jj], smem + (BB) + dB[jj]); \
    _Pragma("unroll") for (int jj = 0; jj < 4; ++jj) pB[jj] += 64; } while (0)

  // ---- 32x32x16 fragment addressing (sigma-swizzle) ----
  const int wr = w >> 1, wc = w & 1;          // 2M x 2N; wave tile 96x64
  const int sl = ((l & 31) >> 1) & 3;         // S(row), lane-const (bases %32==0)
  const int rowA = (wr * 96 + (l & 31)) * 64; // byte base of A row
  const int rowB = (wc * 64 + (l & 31)) * 64; // byte base of B row
  int cks[4];                                  // storage pos byte offset per ks16
#pragma unroll
  for (int ks = 0; ks < 4; ++ks)
    cks[ks] = ((((l >> 5) * 2 + (ks & 1)) ^ sl)) * 16;  // sigma(c) ^ S

  f32x16 acc[3][2];
#pragma unroll
  for (int mh = 0; mh < 3; ++mh)
#pragma unroll
    for (int nh = 0; nh < 2; ++nh)
#pragma unroll
      for (int r = 0; r < 16; ++r) acc[mh][nh][r] = 0.f;
  short8 aF[3][4], bF[2][4];

#define LDA12(BB) do { _Pragma("unroll") for (int mh = 0; mh < 3; ++mh) { \
    _Pragma("unroll") for (int ks = 0; ks < 4; ++ks) \
      aF[mh][ks] = *(const short8*)(smem + (BB) + (ks >> 1) * 12288 + mh * 2048 + rowA + cks[ks]); } } while (0)
#define LDB8(BB) do { _Pragma("unroll") for (int nh = 0; nh < 2; ++nh) { \
    _Pragma("unroll") for (int ks = 0; ks < 4; ++ks) \
      bF[nh][ks] = *(const short8*)(smem + (BB) + P2BOFF + (ks >> 1) * 8192 + nh * 2048 + rowB + cks[ks]); } } while (0)
#define MF12(NH) do { _Pragma("unroll") for (int ks = 0; ks < 4; ++ks) { \
    _Pragma("unroll") for (int mh = 0; mh < 3; ++mh) \
      acc[mh][(NH)] = __builtin_amdgcn_mfma_f32_32x32x16_bf16( \
          aF[mh][ks], bF[(NH)][ks], acc[mh][(NH)], 0, 0, 0); } } while (0)
#define BARR do { __builtin_amdgcn_s_barrier(); asm volatile("" ::: "memory"); } while (0)
#define WAITV(N) do { asm volatile("s_waitcnt vmcnt(" #N ")" ::: "memory"); \
    __builtin_amdgcn_sched_barrier(0); } while (0)
#define PRIO1 __builtin_amdgcn_s_setprio(1)
#define PRIO0 __builtin_amdgcn_s_setprio(0)

  // prologue: A0,B0 -> buf0; A1 -> buf1; drain A0,B0 (leave A1 in flight)
  STGA6(0); STGB4(0);
  STGA6(P2BUF);
  WAITV(6);
  BARR;

  const int nit2 = 32;                         // 64 KTs, 2 per iteration
  for (int t2 = 0; t2 < nit2; ++t2) {
    const bool morA = (t2 + 1 < nit2);
    // ---- KT even (buf0) ----
    LDA12(0); LDB8(0);
    STGB4(P2BUF);                              // B(t+1) -> buf1
    PRIO1; MF12(0); PRIO0;                     // nh0: consumes ALL A reads
    BARR;                                      // seals buf0.A reads (all waves)
    if (morA) STGA6(0);                        // A(t+2) -> buf0
    PRIO1; MF12(1); PRIO0;                     // nh1 (bF from regs)
    if (morA) { WAITV(6); } else { WAITV(0); } // drain A(t+1)+B(t+1)
    BARR;
    // ---- KT odd (buf1) ----
    LDA12(P2BUF); LDB8(P2BUF);
    if (morA) STGB4(0);                        // B(t+2) -> buf0
    PRIO1; MF12(0); PRIO0;
    BARR;
    if (morA) STGA6(P2BUF);                    // A(t+3) -> buf1
    PRIO1; MF12(1); PRIO0;
    if (morA) { WAITV(6); } else { WAITV(0); }
    BARR;
  }

  // ---- epilogue: out += acc + bias (m74 C/D mapping, no atomics) ----
  float bv[2];
#pragma unroll
  for (int nh = 0; nh < 2; ++nh)
    bv[nh] = bias[tn + wc * 64 + nh * 32 + (l & 31)];
#pragma unroll
  for (int mh = 0; mh < 3; ++mh) {
    const int r0 = tm + wr * 96 + mh * 32 + 4 * (l >> 5);
#pragma unroll
    for (int nh = 0; nh < 2; ++nh) {
      const int col = tn + wc * 64 + nh * 32 + (l & 31);
#pragma unroll
      for (int rg = 0; rg < 4; ++rg) {
        float* po = outp + (size_t)(r0 + rg * 8) * EMBED + col;
#pragma unroll
        for (int rr = 0; rr < 4; ++rr)
          po[(size_t)rr * EMBED] += acc[mh][nh][rg * 4 + rr] + bv[nh];
      }
    }
  }
}

// ---- launch -------------------------------------------------------------

extern "C" void kernel_launch(void* const* d_in, const int* in_sizes, int n_in,
                              void* d_out, int out_size, void* d_ws, size_t ws_size,
                              hipStream_t stream) {
  const float* xg[3] = {(const float*)d_in[0], (const float*)d_in[3], (const float*)d_in[6]};
  const float* mg[3] = {(const float*)d_in[1], (const float*)d_in[4], (const float*)d_in[7]};
  const float* tg[3] = {(const float*)d_in[2], (const float*)d_in[5], (const float*)d_in[8]};
  const int* idxg[3] = {(const int*)d_in[9], (const int*)d_in[10], (const int*)d_in[11]};
  const float* W_lin = (const float*)d_in[12];
  const float* b_lin = (const float*)d_in[13];
  const float* W_res = (const float*)d_in[14];
  const float* b_res = (const float*)d_in[15];
  const float* W_out = (const float*)d_in[16];
  const float* b_out = (const float*)d_in[17];
  float* out = (float*)d_out;

  char* ws = (char*)d_ws;
  size_t off = 0;
  auto alloc = [&](size_t b) -> char* {
    size_t o = (off + 255) & ~(size_t)255;
    off = o + b;
    return ws + o;
  };

  ushort_t* hidden = (ushort_t*)alloc((size_t)MROWS * INTER * 2);   // 201 MB
  const int Kp[3] = {64, 96, 192};
  ushort_t* xsw[3];
  ushort_t* wcat[3];
  for (int g = 0; g < 3; ++g) xsw[g]  = (ushort_t*)alloc((size_t)8192 * Kp[g] * 2);
  for (int g = 0; g < 3; ++g) wcat[g] = (ushort_t*)alloc((size_t)NCAT * Kp[g] * 2);
  ushort_t* wout = (ushort_t*)alloc((size_t)EMBED * INTER * 2);     // 8 MB
  float* bcat = (float*)alloc((size_t)NCAT * 4);

  // merged preps: 2 dispatches
  const int wTotal = NCAT + EMBED * INTER + NCAT * 352;   // 6,001,664
  prep_w<<<(wTotal + 255) / 256, 256, 0, stream>>>(
      W_lin, W_res, W_out, b_lin, b_res, wout, wcat[0], wcat[1], wcat[2], bcat);
  const int xTotal = 8192 * 352;                          // 2,883,584
  prep_x<<<(xTotal + 255) / 256, 256, 0, stream>>>(
      xg[0], mg[0], tg[0], xg[1], mg[1], tg[1], xg[2], mg[2], tg[2],
      xsw[0], xsw[1], xsw[2]);

  // phase 1: all 3 groups in ONE dispatch: [8192 x Kp] @ [5120 x Kp]^T each
  gemm128p1g<<<dim3(192, 40), 256, 0, stream>>>(
      xsw[0], xsw[1], xsw[2], wcat[0], wcat[1], wcat[2], bcat,
      hidden, out, idxg[0], idxg[1], idxg[2]);
  // phase 2: [24576 x 4096] @ [1024 x 4096]^T, full K, out += acc + b_out
  gemm192x128<<<dim3(1024), 256, 0, stream>>>(hidden, wout, b_out, out);
}

// Round 17
// 380.898 us; speedup vs baseline: 5.4068x; 1.0188x over previous
//
#include <hip/hip_runtime.h>
#include <hip/hip_bf16.h>
#include <math.h>

typedef unsigned short ushort_t;
typedef short short8 __attribute__((ext_vector_type(8)));
typedef float f32x4 __attribute__((ext_vector_type(4)));

#define N_TOK 512
#define EMBED 1024
#define INTER 4096
#define NCAT  5120   /* INTER + EMBED */
#define MROWS 24576  /* 48 * 512 */

__device__ __forceinline__ ushort_t f2bf(float f) {
  union { float f; unsigned int u; } c; c.f = f;
  unsigned int u = c.u;
  unsigned int r = u + 0x7fffu + ((u >> 16) & 1u);
  return (ushort_t)(r >> 16);
}

__device__ __forceinline__ void gld_lds16(const void* g, void* l) {
  __builtin_amdgcn_global_load_lds(
      (const __attribute__((address_space(1))) void*)g,
      (__attribute__((address_space(3))) void*)l, 16, 0, 0);
}

// ---- merged prep kernels (R10, unchanged) -------------------------------
__global__ void prep_w(const float* __restrict__ Wl, const float* __restrict__ Wr,
                       const float* __restrict__ Wo,
                       const float* __restrict__ bl, const float* __restrict__ br,
                       ushort_t* __restrict__ wout,
                       ushort_t* __restrict__ w0, ushort_t* __restrict__ w1,
                       ushort_t* __restrict__ w2, float* __restrict__ bcat) {
  int i = blockIdx.x * 256 + threadIdx.x;
  if (i < NCAT) { bcat[i] = (i < INTER) ? bl[i] : br[i - INTER]; return; }
  i -= NCAT;
  if (i < EMBED * INTER) { wout[i] = f2bf(Wo[i]); return; }
  i -= EMBED * INTER;
  ushort_t* dst; int Kpad, P3;
  if (i < NCAT * 64)            { dst = w0; Kpad = 64;  P3 = 48; }
  else if (i < NCAT * 160)      { i -= NCAT * 64;  dst = w1; Kpad = 96;  P3 = 96; }
  else if (i < NCAT * 352)      { i -= NCAT * 160; dst = w2; Kpad = 192; P3 = 192; }
  else return;
  const int r = i / Kpad, j = i - r * Kpad;
  float v = 0.f;
  if (j < P3) {
    float scale = 96.0f / (float)P3;
    float src = (j + 0.5f) * scale - 0.5f;
    src = fminf(fmaxf(src, 0.0f), 95.0f);
    int i0 = (int)src;
    int i1 = min(i0 + 1, 95);
    float tt = src - (float)i0;
    const float* Wrow = (r < INTER) ? (Wl + (size_t)r * 96)
                                    : (Wr + (size_t)(r - INTER) * 96);
    v = Wrow[i0] * (1.f - tt) + Wrow[i1] * tt;
  }
  dst[i] = f2bf(v);
}

__global__ void prep_x(const float* __restrict__ x0, const float* __restrict__ m0,
                       const float* __restrict__ t0,
                       const float* __restrict__ x1, const float* __restrict__ m1,
                       const float* __restrict__ t1,
                       const float* __restrict__ x2, const float* __restrict__ m2,
                       const float* __restrict__ t2,
                       ushort_t* __restrict__ d0, ushort_t* __restrict__ d1,
                       ushort_t* __restrict__ d2) {
  int i = blockIdx.x * 256 + threadIdx.x;
  const float *x, *m, *t; ushort_t* dst; int p, Kpad;
  if (i < 8192 * 64)            { x = x0; m = m0; t = t0; dst = d0; p = 16; Kpad = 64; }
  else if (i < 8192 * 160)      { i -= 8192 * 64;  x = x1; m = m1; t = t1; dst = d1; p = 32; Kpad = 96; }
  else if (i < 8192 * 352)      { i -= 8192 * 160; x = x2; m = m2; t = t2; dst = d2; p = 64; Kpad = 192; }
  else return;
  const int r = i / Kpad, j = i - r * Kpad;
  float v = 0.f;
  const int p3 = 3 * p;
  if (j < p3) {
    size_t base = (size_t)r * p;
    if (j < p)           v = x[base + j];
    else if (j < 2 * p)  v = m[base + j - p];
    else                 v = t[base + j - 2 * p];
  }
  dst[i] = f2bf(v);
}

// ---- phase-1: 128x256 GEMM, BK=32, 4 waves (2Mx2N, wave 64x128) --------
// MFMA:read = 32:12 per wave-KT (vs 16:8 in the old 128x128). Proven
// components only: R10 staging (16-row 1KB chunks, XOR chunk swizzle,
// gld_lds), R3 2-phase ledger (stage next -> vmcnt(6) -> barrier ->
// compute -> barrier), R10 fragment addressing (0-conflict).
// Grid dim3(192, 20): bx = group*64 + mtile(128), by = ntile(256).
// LDS 2 x (A 8KB + B 16KB) = 48KB -> 3 blocks/CU.
// Epilogue: by<16 -> all-hidden (silu+bf16); by>=16 -> all-res (f32 out).
#define P1BUF 24576
#define P1BOFF 8192

__global__ __launch_bounds__(256, 2)
void gemm128x256p1(const ushort_t* __restrict__ A0, const ushort_t* __restrict__ A1,
                   const ushort_t* __restrict__ A2,
                   const ushort_t* __restrict__ B0w, const ushort_t* __restrict__ B1w,
                   const ushort_t* __restrict__ B2w,
                   const float* __restrict__ bias,
                   ushort_t* __restrict__ hidden, float* __restrict__ outp,
                   const int* __restrict__ i0, const int* __restrict__ i1,
                   const int* __restrict__ i2) {
  __shared__ __align__(16) char smem[2 * P1BUF];
  const int tid = threadIdx.x;
  const int w = tid >> 6, l = tid & 63;

  const int gm = blockIdx.x >> 6;             // group 0/1/2
  const int tm = (blockIdx.x & 63) * 128;     // within-group row tile
  const int tn = blockIdx.y * 256;
  const ushort_t* A = (gm == 0) ? A0 : (gm == 1) ? A1 : A2;
  const ushort_t* B = (gm == 0) ? B0w : (gm == 1) ? B1w : B2w;
  const int* idxg   = (gm == 0) ? i0 : (gm == 1) ? i1 : i2;
  const int Kpad    = (gm == 0) ? 64 : (gm == 1) ? 96 : 192;

  // staging pointers: A 8 chunks (2/wave), B 16 chunks (4/wave); 16-row
  // 1KB chunks, source chunk XOR-swizzled (R10-proven, rule 21).
  const ushort_t* pA[2]; int dA[2];
#pragma unroll
  for (int jj = 0; jj < 2; ++jj) {
    const int q = w * 2 + jj;                 // 0..7
    const int row = q * 16 + (l >> 2);
    const int c = (l & 3) ^ ((row >> 1) & 3);
    pA[jj] = A + (size_t)(tm + row) * Kpad + c * 8;
    dA[jj] = q * 1024;
  }
  const ushort_t* pB[4]; int dB[4];
#pragma unroll
  for (int jj = 0; jj < 4; ++jj) {
    const int q = w * 4 + jj;                 // 0..15
    const int row = q * 16 + (l >> 2);
    const int c = (l & 3) ^ ((row >> 1) & 3);
    pB[jj] = B + (size_t)(tn + row) * Kpad + c * 8;
    dB[jj] = P1BOFF + q * 1024;
  }

#define P1STGA(BB) do { _Pragma("unroll") for (int jj = 0; jj < 2; ++jj) \
    gld_lds16(pA[jj], smem + (BB) + dA[jj]); \
    _Pragma("unroll") for (int jj = 0; jj < 2; ++jj) pA[jj] += 32; } while (0)
#define P1STGB(BB) do { _Pragma("unroll") for (int jj = 0; jj < 4; ++jj) \
    gld_lds16(pB[jj], smem + (BB) + dB[jj]); \
    _Pragma("unroll") for (int jj = 0; jj < 4; ++jj) pB[jj] += 32; } while (0)

  // fragment read bases (R10 pattern, conflict-free)
  const int wr = w >> 1, wc = w & 1;          // 2M x 2N; wave tile 64x128
  const int xl = ((l & 15) >> 1) & 3;
  const int cx = ((l >> 4) ^ xl) * 16;
  const int aBase = (wr * 64 + (l & 15)) * 64 + cx;
  const int bBase = P1BOFF + (wc * 128 + (l & 15)) * 64 + cx;

  f32x4 acc[4][8];
  const f32x4 zero = {0.f, 0.f, 0.f, 0.f};
#pragma unroll
  for (int m2 = 0; m2 < 4; ++m2)
#pragma unroll
    for (int n2 = 0; n2 < 8; ++n2) acc[m2][n2] = zero;
  short8 aF[4], bF[8];

#define P1LDA(BB) do { _Pragma("unroll") for (int m2 = 0; m2 < 4; ++m2) \
    aF[m2] = *(const short8*)(smem + (BB) + m2 * 1024 + aBase); } while (0)
#define P1LDB(BB) do { _Pragma("unroll") for (int n2 = 0; n2 < 8; ++n2) \
    bF[n2] = *(const short8*)(smem + (BB) + n2 * 1024 + bBase); } while (0)
#define P1MF() do { _Pragma("unroll") for (int m2 = 0; m2 < 4; ++m2) { \
    _Pragma("unroll") for (int n2 = 0; n2 < 8; ++n2) \
      acc[m2][n2] = __builtin_amdgcn_mfma_f32_16x16x32_bf16( \
          aF[m2], bF[n2], acc[m2][n2], 0, 0, 0); } } while (0)
#define BARR do { __builtin_amdgcn_s_barrier(); asm volatile("" ::: "memory"); } while (0)
#define WAITV(N) do { asm volatile("s_waitcnt vmcnt(" #N ")" ::: "memory"); \
    __builtin_amdgcn_sched_barrier(0); } while (0)
#define PRIO1 __builtin_amdgcn_s_setprio(1)
#define PRIO0 __builtin_amdgcn_s_setprio(0)

  const int nk = Kpad >> 5;                    // 2 / 3 / 6
  P1STGA(0); P1STGB(0);                        // KT0 -> buf0
  for (int kk = 0; kk < nk; ++kk) {
    const int cur = kk & 1;
    if (kk + 1 < nk) {
      const int nxt = cur ^ 1;
      P1STGA(nxt * P1BUF); P1STGB(nxt * P1BUF);   // KT(kk+1)
      WAITV(6);                                    // KT(kk) landed
    } else {
      WAITV(0);
    }
    BARR;
    P1LDA(cur * P1BUF); P1LDB(cur * P1BUF);
    PRIO1; P1MF(); PRIO0;
    BARR;                                          // seal reads before restage
  }

  const int layer = idxg[tm >> 9];
  const int rowBase = layer * N_TOK + (tm & (N_TOK - 1));
  const bool hid = (tn < INTER);                   // block-uniform (by<16)

#pragma unroll
  for (int m2 = 0; m2 < 4; ++m2) {
#pragma unroll
    for (int n2 = 0; n2 < 8; ++n2) {
      const int colg = tn + wc * 128 + n2 * 16 + (l & 15);
      const float bv = bias[colg];
#pragma unroll
      for (int r = 0; r < 4; ++r) {
        const int rowl = wr * 64 + m2 * 16 + (l >> 4) * 4 + r;
        const float v = acc[m2][n2][r];
        const int grow = rowBase + rowl;
        if (hid) {
          float h = v + bv;
          h = h / (1.f + expf(-h));
          hidden[(size_t)grow * INTER + colg] = f2bf(h);
        } else {
          outp[(size_t)grow * EMBED + (colg - INTER)] = v + bv;
        }
      }
    }
  }
}

// ---- phase-2: 192x128 full-K GEMM (R10 verbatim — known 221 us) --------
#define P2BUF 40960
#define P2BOFF 24576

__global__ __launch_bounds__(256, 2)
void gemm192x128(const ushort_t* __restrict__ A, const ushort_t* __restrict__ Bw,
                 const float* __restrict__ bias, float* __restrict__ outp) {
  __shared__ __align__(16) char smem[2 * P2BUF];
  const int tid = threadIdx.x;
  const int w = tid >> 6, l = tid & 63;

  const int L = blockIdx.x;
  const int xcd = L & 7, j = L >> 3;          // j in [0,128)
  const int nt = j & 7, mtl = j >> 3;         // nt fastest: A-slab reuse
  const int tm = (xcd * 16 + mtl) * 192, tn = nt * 128;

  const ushort_t* pA[6]; int dA[6];
#pragma unroll
  for (int jj = 0; jj < 6; ++jj) {
    const int q = w * 6 + jj;                 // 0..23
    const int ks = q / 12, rb = q % 12;
    const int row = rb * 16 + (l >> 2);
    const int c = (l & 3) ^ ((row >> 1) & 3);
    pA[jj] = A + (size_t)(tm + row) * 4096 + ks * 32 + c * 8;
    dA[jj] = ks * 12288 + rb * 1024;
  }
  const ushort_t* pB[4]; int dB[4];
#pragma unroll
  for (int jj = 0; jj < 4; ++jj) {
    const int q = w * 4 + jj;                 // 0..15
    const int ks = q >> 3, rb = q & 7;
    const int row = rb * 16 + (l >> 2);
    const int c = (l & 3) ^ ((row >> 1) & 3);
    pB[jj] = Bw + (size_t)(tn + row) * 4096 + ks * 32 + c * 8;
    dB[jj] = P2BOFF + ks * 8192 + rb * 1024;
  }

#define STGA6(BB) do { _Pragma("unroll") for (int jj = 0; jj < 6; ++jj) \
    gld_lds16(pA[jj], smem + (BB) + dA[jj]); \
    _Pragma("unroll") for (int jj = 0; jj < 6; ++jj) pA[jj] += 64; } while (0)
#define STGB4(BB) do { _Pragma("unroll") for (int jj = 0; jj < 4; ++jj) \
    gld_lds16(pB[jj], smem + (BB) + dB[jj]); \
    _Pragma("unroll") for (int jj = 0; jj < 4; ++jj) pB[jj] += 64; } while (0)

  const int wr = w >> 1, wc = w & 1;          // 2M x 2N
  const int xl = ((l & 15) >> 1) & 3;
  const int cx = ((l >> 4) ^ xl) * 16;
  const int aBase = (wr * 96 + (l & 15)) * 64 + cx;
  const int bBase = P2BOFF + (wc * 64 + (l & 15)) * 64 + cx;

  f32x4 acc[6][4];
  const f32x4 zero = {0.f, 0.f, 0.f, 0.f};
#pragma unroll
  for (int m = 0; m < 6; ++m)
#pragma unroll
    for (int n = 0; n < 4; ++n) acc[m][n] = zero;
  short8 aF2[6][2], bF[2][2], bF2[2][2];

#define LDA12(BB) do { _Pragma("unroll") for (int mp = 0; mp < 6; ++mp) { \
    _Pragma("unroll") for (int ks = 0; ks < 2; ++ks) \
      aF2[mp][ks] = *(const short8*)(smem + (BB) + ks * 12288 + mp * 1024 + aBase); } } while (0)
#define LDB4(D, BB, NH) do { _Pragma("unroll") for (int np = 0; np < 2; ++np) { \
    _Pragma("unroll") for (int ks = 0; ks < 2; ++ks) \
      D[np][ks] = *(const short8*)(smem + (BB) + ks * 8192 + (NH) * 2048 + np * 1024 + bBase); } } while (0)
#define QUAD24(NH, FB) do { _Pragma("unroll") for (int mp = 0; mp < 6; ++mp) { \
    _Pragma("unroll") for (int np = 0; np < 2; ++np) { \
      _Pragma("unroll") for (int ks = 0; ks < 2; ++ks) \
        acc[mp][(NH)*2+np] = __builtin_amdgcn_mfma_f32_16x16x32_bf16( \
            aF2[mp][ks], FB[np][ks], acc[mp][(NH)*2+np], 0, 0, 0); } } } while (0)

  // prologue: A0,B0 -> buf0; A1 -> buf1; drain A0,B0 (leave A1 in flight)
  STGA6(0); STGB4(0);
  STGA6(P2BUF);
  WAITV(6);
  BARR;

  const int nit2 = 32;                         // 64 KTs, 2 per iteration
  for (int t2 = 0; t2 < nit2; ++t2) {
    const bool morA = (t2 + 1 < nit2);
    // ---- KT even (buf0) ----
    LDA12(0); LDB4(bF, 0, 0); LDB4(bF2, 0, 1);
    STGB4(P2BUF);                              // B(t+1) -> buf1
    PRIO1; QUAD24(0, bF); PRIO0;
    BARR;                                      // seals all waves' buf0 reads
    if (morA) STGA6(0);                        // A(t+2) -> buf0
    PRIO1; QUAD24(1, bF2); PRIO0;
    if (morA) { WAITV(6); } else { WAITV(0); } // drain KT(t+1) data
    BARR;
    // ---- KT odd (buf1) ----
    LDA12(P2BUF); LDB4(bF, P2BUF, 0); LDB4(bF2, P2BUF, 1);
    if (morA) STGB4(0);                        // B(t+2) -> buf0
    PRIO1; QUAD24(0, bF); PRIO0;
    BARR;
    if (morA) STGA6(P2BUF);                    // A(t+3) -> buf1
    PRIO1; QUAD24(1, bF2); PRIO0;
    if (morA) { WAITV(6); } else { WAITV(0); }
    BARR;
  }

  // epilogue: out += acc + bias (single writer, no atomics)
  float bv[4];
#pragma unroll
  for (int n = 0; n < 4; ++n)
    bv[n] = bias[tn + wc * 64 + (n >> 1) * 32 + (n & 1) * 16 + (l & 15)];
#pragma unroll
  for (int m = 0; m < 6; ++m) {
    const int row = tm + wr * 96 + m * 16 + (l >> 4) * 4;
#pragma unroll
    for (int n = 0; n < 4; ++n) {
      const int col = tn + wc * 64 + (n >> 1) * 32 + (n & 1) * 16 + (l & 15);
      float* po = outp + (size_t)row * EMBED + col;
#pragma unroll
      for (int ri = 0; ri < 4; ++ri)
        po[(size_t)ri * EMBED] += acc[m][n][ri] + bv[n];
    }
  }
}

// ---- launch -------------------------------------------------------------

extern "C" void kernel_launch(void* const* d_in, const int* in_sizes, int n_in,
                              void* d_out, int out_size, void* d_ws, size_t ws_size,
                              hipStream_t stream) {
  const float* xg[3] = {(const float*)d_in[0], (const float*)d_in[3], (const float*)d_in[6]};
  const float* mg[3] = {(const float*)d_in[1], (const float*)d_in[4], (const float*)d_in[7]};
  const float* tg[3] = {(const float*)d_in[2], (const float*)d_in[5], (const float*)d_in[8]};
  const int* idxg[3] = {(const int*)d_in[9], (const int*)d_in[10], (const int*)d_in[11]};
  const float* W_lin = (const float*)d_in[12];
  const float* b_lin = (const float*)d_in[13];
  const float* W_res = (const float*)d_in[14];
  const float* b_res = (const float*)d_in[15];
  const float* W_out = (const float*)d_in[16];
  const float* b_out = (const float*)d_in[17];
  float* out = (float*)d_out;

  char* ws = (char*)d_ws;
  size_t off = 0;
  auto alloc = [&](size_t b) -> char* {
    size_t o = (off + 255) & ~(size_t)255;
    off = o + b;
    return ws + o;
  };

  ushort_t* hidden = (ushort_t*)alloc((size_t)MROWS * INTER * 2);   // 201 MB
  const int Kp[3] = {64, 96, 192};
  ushort_t* xsw[3];
  ushort_t* wcat[3];
  for (int g = 0; g < 3; ++g) xsw[g]  = (ushort_t*)alloc((size_t)8192 * Kp[g] * 2);
  for (int g = 0; g < 3; ++g) wcat[g] = (ushort_t*)alloc((size_t)NCAT * Kp[g] * 2);
  ushort_t* wout = (ushort_t*)alloc((size_t)EMBED * INTER * 2);     // 8 MB
  float* bcat = (float*)alloc((size_t)NCAT * 4);

  // merged preps: 2 dispatches
  const int wTotal = NCAT + EMBED * INTER + NCAT * 352;   // 6,001,664
  prep_w<<<(wTotal + 255) / 256, 256, 0, stream>>>(
      W_lin, W_res, W_out, b_lin, b_res, wout, wcat[0], wcat[1], wcat[2], bcat);
  const int xTotal = 8192 * 352;                          // 2,883,584
  prep_x<<<(xTotal + 255) / 256, 256, 0, stream>>>(
      xg[0], mg[0], tg[0], xg[1], mg[1], tg[1], xg[2], mg[2], tg[2],
      xsw[0], xsw[1], xsw[2]);

  // phase 1: all 3 groups, 128x256 tiles: grid (3*64, 5120/256)
  gemm128x256p1<<<dim3(192, 20), 256, 0, stream>>>(
      xsw[0], xsw[1], xsw[2], wcat[0], wcat[1], wcat[2], bcat,
      hidden, out, idxg[0], idxg[1], idxg[2]);
  // phase 2: [24576 x 4096] @ [1024 x 4096]^T, full K, out += acc + b_out
  gemm192x128<<<dim3(1024), 256, 0, stream>>>(hidden, wout, b_out, out);
}

// Round 18
// 357.273 us; speedup vs baseline: 5.7643x; 1.0661x over previous
//
#include <hip/hip_runtime.h>
#include <hip/hip_bf16.h>
#include <math.h>

typedef unsigned short ushort_t;
typedef short short8 __attribute__((ext_vector_type(8)));
typedef float f32x4 __attribute__((ext_vector_type(4)));

#define N_TOK 512
#define EMBED 1024
#define INTER 4096
#define NCAT  5120   /* INTER + EMBED */
#define MROWS 24576  /* 48 * 512 */

__device__ __forceinline__ ushort_t f2bf(float f) {
  union { float f; unsigned int u; } c; c.f = f;
  unsigned int u = c.u;
  unsigned int r = u + 0x7fffu + ((u >> 16) & 1u);
  return (ushort_t)(r >> 16);
}

__device__ __forceinline__ float bf2f(ushort_t h) {
  union { unsigned int u; float f; } c; c.u = ((unsigned int)h) << 16;
  return c.f;
}

__device__ __forceinline__ void gld_lds16(const void* g, void* l) {
  __builtin_amdgcn_global_load_lds(
      (const __attribute__((address_space(1))) void*)g,
      (__attribute__((address_space(3))) void*)l, 16, 0, 0);
}

// ---- merged prep kernels (R10, unchanged) -------------------------------
__global__ void prep_w(const float* __restrict__ Wl, const float* __restrict__ Wr,
                       const float* __restrict__ Wo,
                       const float* __restrict__ bl, const float* __restrict__ br,
                       ushort_t* __restrict__ wout,
                       ushort_t* __restrict__ w0, ushort_t* __restrict__ w1,
                       ushort_t* __restrict__ w2, float* __restrict__ bcat) {
  int i = blockIdx.x * 256 + threadIdx.x;
  if (i < NCAT) { bcat[i] = (i < INTER) ? bl[i] : br[i - INTER]; return; }
  i -= NCAT;
  if (i < EMBED * INTER) { wout[i] = f2bf(Wo[i]); return; }
  i -= EMBED * INTER;
  ushort_t* dst; int Kpad, P3;
  if (i < NCAT * 64)            { dst = w0; Kpad = 64;  P3 = 48; }
  else if (i < NCAT * 160)      { i -= NCAT * 64;  dst = w1; Kpad = 96;  P3 = 96; }
  else if (i < NCAT * 352)      { i -= NCAT * 160; dst = w2; Kpad = 192; P3 = 192; }
  else return;
  const int r = i / Kpad, j = i - r * Kpad;
  float v = 0.f;
  if (j < P3) {
    float scale = 96.0f / (float)P3;
    float src = (j + 0.5f) * scale - 0.5f;
    src = fminf(fmaxf(src, 0.0f), 95.0f);
    int i0 = (int)src;
    int i1 = min(i0 + 1, 95);
    float tt = src - (float)i0;
    const float* Wrow = (r < INTER) ? (Wl + (size_t)r * 96)
                                    : (Wr + (size_t)(r - INTER) * 96);
    v = Wrow[i0] * (1.f - tt) + Wrow[i1] * tt;
  }
  dst[i] = f2bf(v);
}

__global__ void prep_x(const float* __restrict__ x0, const float* __restrict__ m0,
                       const float* __restrict__ t0,
                       const float* __restrict__ x1, const float* __restrict__ m1,
                       const float* __restrict__ t1,
                       const float* __restrict__ x2, const float* __restrict__ m2,
                       const float* __restrict__ t2,
                       ushort_t* __restrict__ d0, ushort_t* __restrict__ d1,
                       ushort_t* __restrict__ d2) {
  int i = blockIdx.x * 256 + threadIdx.x;
  const float *x, *m, *t; ushort_t* dst; int p, Kpad;
  if (i < 8192 * 64)            { x = x0; m = m0; t = t0; dst = d0; p = 16; Kpad = 64; }
  else if (i < 8192 * 160)      { i -= 8192 * 64;  x = x1; m = m1; t = t1; dst = d1; p = 32; Kpad = 96; }
  else if (i < 8192 * 352)      { i -= 8192 * 160; x = x2; m = m2; t = t2; dst = d2; p = 64; Kpad = 192; }
  else return;
  const int r = i / Kpad, j = i - r * Kpad;
  float v = 0.f;
  const int p3 = 3 * p;
  if (j < p3) {
    size_t base = (size_t)r * p;
    if (j < p)           v = x[base + j];
    else if (j < 2 * p)  v = m[base + j - p];
    else                 v = t[base + j - 2 * p];
  }
  dst[i] = f2bf(v);
}

// ---- phase-1: merged 3-group 128x128 GEMM (R10 core, proven) ------------
// RB=1: residual -> bf16 rbuf (phase-2 adds it); RB=0: residual -> f32 out.
template <int RB>
__global__ __launch_bounds__(256)
void gemm128p1g(const ushort_t* __restrict__ A0, const ushort_t* __restrict__ A1,
                const ushort_t* __restrict__ A2,
                const ushort_t* __restrict__ B0w, const ushort_t* __restrict__ B1w,
                const ushort_t* __restrict__ B2w,
                const float* __restrict__ bias,
                ushort_t* __restrict__ hidden, float* __restrict__ outp,
                ushort_t* __restrict__ rbuf,
                const int* __restrict__ i0, const int* __restrict__ i1,
                const int* __restrict__ i2) {
  __shared__ __align__(16) ushort_t lA[2][128 * 32];
  __shared__ __align__(16) ushort_t lB[2][128 * 32];
  const int t = threadIdx.x;
  const int wave = t >> 6, lane = t & 63;
  const int gm = blockIdx.x >> 6;             // group 0/1/2
  const int tm = (blockIdx.x & 63) * 128;     // within-group row tile
  const int tn = blockIdx.y * 128;
  const ushort_t* A = (gm == 0) ? A0 : (gm == 1) ? A1 : A2;
  const ushort_t* B = (gm == 0) ? B0w : (gm == 1) ? B1w : B2w;
  const int* idxg   = (gm == 0) ? i0 : (gm == 1) ? i1 : i2;
  const int Kpad    = (gm == 0) ? 64 : (gm == 1) ? 96 : 192;

  const int chunk = wave * 2;
  const int srow = chunk * 16 + (lane >> 2);
  const int scol = (((lane & 3) ^ ((lane >> 3) & 3)) * 8);
  const ushort_t* gA0 = A + (size_t)(tm + srow) * Kpad + scol;
  const ushort_t* gA1 = gA0 + (size_t)16 * Kpad;
  const ushort_t* gB0 = B + (size_t)(tn + srow) * Kpad + scol;
  const ushort_t* gB1 = gB0 + (size_t)16 * Kpad;
  const int ldsOff0 = chunk * 512;
  const int ldsOff1 = ldsOff0 + 512;

  const int wr = wave >> 1, wc = wave & 1;
  const f32x4 zero = {0.f, 0.f, 0.f, 0.f};
  f32x4 acc[4][4];
#pragma unroll
  for (int m2 = 0; m2 < 4; ++m2)
#pragma unroll
    for (int n2 = 0; n2 < 4; ++n2) acc[m2][n2] = zero;

  const int xf = ((lane & 15) >> 1) & 3;
  const int fcol = (((lane >> 4) ^ xf)) * 8;
  const int aoff = (wr * 64 + (lane & 15)) * 32 + fcol;
  const int boff = (wc * 64 + (lane & 15)) * 32 + fcol;

  const int nk = Kpad >> 5;
  gld_lds16(gA0, &lA[0][ldsOff0]); gld_lds16(gA1, &lA[0][ldsOff1]);
  gld_lds16(gB0, &lB[0][ldsOff0]); gld_lds16(gB1, &lB[0][ldsOff1]);
  gA0 += 32; gA1 += 32; gB0 += 32; gB1 += 32;

  for (int kk = 0; kk < nk; ++kk) {
    const int cur = kk & 1;
    if (kk + 1 < nk) {
      const int nxt = cur ^ 1;
      gld_lds16(gA0, &lA[nxt][ldsOff0]); gld_lds16(gA1, &lA[nxt][ldsOff1]);
      gld_lds16(gB0, &lB[nxt][ldsOff0]); gld_lds16(gB1, &lB[nxt][ldsOff1]);
      gA0 += 32; gA1 += 32; gB0 += 32; gB1 += 32;
      asm volatile("s_waitcnt vmcnt(4)" ::: "memory");
    } else {
      asm volatile("s_waitcnt vmcnt(0)" ::: "memory");
    }
    __builtin_amdgcn_s_barrier();
    asm volatile("" ::: "memory");

    const ushort_t* pa = &lA[cur][0] + aoff;
    const ushort_t* pb = &lB[cur][0] + boff;
    short8 aF[4], bF[4];
#pragma unroll
    for (int m2 = 0; m2 < 4; ++m2) aF[m2] = *(const short8*)(pa + m2 * 16 * 32);
#pragma unroll
    for (int n2 = 0; n2 < 4; ++n2) bF[n2] = *(const short8*)(pb + n2 * 16 * 32);
#pragma unroll
    for (int m2 = 0; m2 < 4; ++m2)
#pragma unroll
      for (int n2 = 0; n2 < 4; ++n2)
        acc[m2][n2] = __builtin_amdgcn_mfma_f32_16x16x32_bf16(
            aF[m2], bF[n2], acc[m2][n2], 0, 0, 0);
    __builtin_amdgcn_s_barrier();
    asm volatile("" ::: "memory");
  }

  const int layer = idxg[tm >> 9];
  const int rowBase = layer * N_TOK + (tm & (N_TOK - 1));

#pragma unroll
  for (int m2 = 0; m2 < 4; ++m2) {
#pragma unroll
    for (int n2 = 0; n2 < 4; ++n2) {
      const int colg = tn + wc * 64 + n2 * 16 + (lane & 15);
      const float bv = bias[colg];
#pragma unroll
      for (int r = 0; r < 4; ++r) {
        const int rowl = wr * 64 + m2 * 16 + (lane >> 4) * 4 + r;
        const float v = acc[m2][n2][r];
        const int grow = rowBase + rowl;
        if (colg < INTER) {
          float h = v + bv;
          h = h / (1.f + expf(-h));
          hidden[(size_t)grow * INTER + colg] = f2bf(h);
        } else if (RB) {
          rbuf[(size_t)grow * EMBED + (colg - INTER)] = f2bf(v + bv);
        } else {
          outp[(size_t)grow * EMBED + (colg - INTER)] = v + bv;
        }
      }
    }
  }
}

// ---- phase-2: 192x128 full-K GEMM (R10 core — known 221 us) -------------
// RB=1: out = acc + bias + bf16-res (pure store, no RMW);
// RB=0: out += acc + bias (legacy).
#define P2BUF 40960
#define P2BOFF 24576

template <int RB>
__global__ __launch_bounds__(256, 2)
void gemm192x128(const ushort_t* __restrict__ A, const ushort_t* __restrict__ Bw,
                 const float* __restrict__ bias, float* __restrict__ outp,
                 const ushort_t* __restrict__ rbuf) {
  __shared__ __align__(16) char smem[2 * P2BUF];
  const int tid = threadIdx.x;
  const int w = tid >> 6, l = tid & 63;

  const int L = blockIdx.x;
  const int xcd = L & 7, j = L >> 3;          // j in [0,128)
  const int nt = j & 7, mtl = j >> 3;         // nt fastest: A-slab reuse
  const int tm = (xcd * 16 + mtl) * 192, tn = nt * 128;

  const ushort_t* pA[6]; int dA[6];
#pragma unroll
  for (int jj = 0; jj < 6; ++jj) {
    const int q = w * 6 + jj;                 // 0..23
    const int ks = q / 12, rb = q % 12;
    const int row = rb * 16 + (l >> 2);
    const int c = (l & 3) ^ ((row >> 1) & 3);
    pA[jj] = A + (size_t)(tm + row) * 4096 + ks * 32 + c * 8;
    dA[jj] = ks * 12288 + rb * 1024;
  }
  const ushort_t* pB[4]; int dB[4];
#pragma unroll
  for (int jj = 0; jj < 4; ++jj) {
    const int q = w * 4 + jj;                 // 0..15
    const int ks = q >> 3, rb = q & 7;
    const int row = rb * 16 + (l >> 2);
    const int c = (l & 3) ^ ((row >> 1) & 3);
    pB[jj] = Bw + (size_t)(tn + row) * 4096 + ks * 32 + c * 8;
    dB[jj] = P2BOFF + ks * 8192 + rb * 1024;
  }

#define STGA6(BB) do { _Pragma("unroll") for (int jj = 0; jj < 6; ++jj) \
    gld_lds16(pA[jj], smem + (BB) + dA[jj]); \
    _Pragma("unroll") for (int jj = 0; jj < 6; ++jj) pA[jj] += 64; } while (0)
#define STGB4(BB) do { _Pragma("unroll") for (int jj = 0; jj < 4; ++jj) \
    gld_lds16(pB[jj], smem + (BB) + dB[jj]); \
    _Pragma("unroll") for (int jj = 0; jj < 4; ++jj) pB[jj] += 64; } while (0)

  const int wr = w >> 1, wc = w & 1;          // 2M x 2N
  const int xl = ((l & 15) >> 1) & 3;
  const int cx = ((l >> 4) ^ xl) * 16;
  const int aBase = (wr * 96 + (l & 15)) * 64 + cx;
  const int bBase = P2BOFF + (wc * 64 + (l & 15)) * 64 + cx;

  f32x4 acc[6][4];
  const f32x4 zero = {0.f, 0.f, 0.f, 0.f};
#pragma unroll
  for (int m = 0; m < 6; ++m)
#pragma unroll
    for (int n = 0; n < 4; ++n) acc[m][n] = zero;
  short8 aF2[6][2], bF[2][2], bF2[2][2];

#define LDA12(BB) do { _Pragma("unroll") for (int mp = 0; mp < 6; ++mp) { \
    _Pragma("unroll") for (int ks = 0; ks < 2; ++ks) \
      aF2[mp][ks] = *(const short8*)(smem + (BB) + ks * 12288 + mp * 1024 + aBase); } } while (0)
#define LDB4(D, BB, NH) do { _Pragma("unroll") for (int np = 0; np < 2; ++np) { \
    _Pragma("unroll") for (int ks = 0; ks < 2; ++ks) \
      D[np][ks] = *(const short8*)(smem + (BB) + ks * 8192 + (NH) * 2048 + np * 1024 + bBase); } } while (0)
#define QUAD24(NH, FB) do { _Pragma("unroll") for (int mp = 0; mp < 6; ++mp) { \
    _Pragma("unroll") for (int np = 0; np < 2; ++np) { \
      _Pragma("unroll") for (int ks = 0; ks < 2; ++ks) \
        acc[mp][(NH)*2+np] = __builtin_amdgcn_mfma_f32_16x16x32_bf16( \
            aF2[mp][ks], FB[np][ks], acc[mp][(NH)*2+np], 0, 0, 0); } } } while (0)
#define BARR do { __builtin_amdgcn_s_barrier(); asm volatile("" ::: "memory"); } while (0)
#define WAITV(N) do { asm volatile("s_waitcnt vmcnt(" #N ")" ::: "memory"); \
    __builtin_amdgcn_sched_barrier(0); } while (0)
#define PRIO1 __builtin_amdgcn_s_setprio(1)
#define PRIO0 __builtin_amdgcn_s_setprio(0)

  // prologue: A0,B0 -> buf0; A1 -> buf1; drain A0,B0 (leave A1 in flight)
  STGA6(0); STGB4(0);
  STGA6(P2BUF);
  WAITV(6);
  BARR;

  const int nit2 = 32;                         // 64 KTs, 2 per iteration
  for (int t2 = 0; t2 < nit2; ++t2) {
    const bool morA = (t2 + 1 < nit2);
    // ---- KT even (buf0) ----
    LDA12(0); LDB4(bF, 0, 0); LDB4(bF2, 0, 1);
    STGB4(P2BUF);                              // B(t+1) -> buf1
    PRIO1; QUAD24(0, bF); PRIO0;
    BARR;                                      // seals all waves' buf0 reads
    if (morA) STGA6(0);                        // A(t+2) -> buf0
    PRIO1; QUAD24(1, bF2); PRIO0;
    if (morA) { WAITV(6); } else { WAITV(0); } // drain KT(t+1) data
    BARR;
    // ---- KT odd (buf1) ----
    LDA12(P2BUF); LDB4(bF, P2BUF, 0); LDB4(bF2, P2BUF, 1);
    if (morA) STGB4(0);                        // B(t+2) -> buf0
    PRIO1; QUAD24(0, bF); PRIO0;
    BARR;
    if (morA) STGA6(P2BUF);                    // A(t+3) -> buf1
    PRIO1; QUAD24(1, bF2); PRIO0;
    if (morA) { WAITV(6); } else { WAITV(0); }
    BARR;
  }

  // epilogue: out = acc + bias (+ bf16 res, pure store) | out += (legacy)
  float bv[4];
#pragma unroll
  for (int n = 0; n < 4; ++n)
    bv[n] = bias[tn + wc * 64 + (n >> 1) * 32 + (n & 1) * 16 + (l & 15)];
#pragma unroll
  for (int m = 0; m < 6; ++m) {
    const int row = tm + wr * 96 + m * 16 + (l >> 4) * 4;
#pragma unroll
    for (int n = 0; n < 4; ++n) {
      const int col = tn + wc * 64 + (n >> 1) * 32 + (n & 1) * 16 + (l & 15);
      float* po = outp + (size_t)row * EMBED + col;
      if (RB) {
        const ushort_t* pr = rbuf + (size_t)row * EMBED + col;
#pragma unroll
        for (int ri = 0; ri < 4; ++ri)
          po[(size_t)ri * EMBED] =
              acc[m][n][ri] + bv[n] + bf2f(pr[(size_t)ri * EMBED]);
      } else {
#pragma unroll
        for (int ri = 0; ri < 4; ++ri)
          po[(size_t)ri * EMBED] += acc[m][n][ri] + bv[n];
      }
    }
  }
}

// ---- launch -------------------------------------------------------------

extern "C" void kernel_launch(void* const* d_in, const int* in_sizes, int n_in,
                              void* d_out, int out_size, void* d_ws, size_t ws_size,
                              hipStream_t stream) {
  const float* xg[3] = {(const float*)d_in[0], (const float*)d_in[3], (const float*)d_in[6]};
  const float* mg[3] = {(const float*)d_in[1], (const float*)d_in[4], (const float*)d_in[7]};
  const float* tg[3] = {(const float*)d_in[2], (const float*)d_in[5], (const float*)d_in[8]};
  const int* idxg[3] = {(const int*)d_in[9], (const int*)d_in[10], (const int*)d_in[11]};
  const float* W_lin = (const float*)d_in[12];
  const float* b_lin = (const float*)d_in[13];
  const float* W_res = (const float*)d_in[14];
  const float* b_res = (const float*)d_in[15];
  const float* W_out = (const float*)d_in[16];
  const float* b_out = (const float*)d_in[17];
  float* out = (float*)d_out;

  char* ws = (char*)d_ws;
  size_t off = 0;
  auto alloc = [&](size_t b) -> char* {
    size_t o = (off + 255) & ~(size_t)255;
    off = o + b;
    return ws + o;
  };

  ushort_t* hidden = (ushort_t*)alloc((size_t)MROWS * INTER * 2);   // 201 MB
  const int Kp[3] = {64, 96, 192};
  ushort_t* xsw[3];
  ushort_t* wcat[3];
  for (int g = 0; g < 3; ++g) xsw[g]  = (ushort_t*)alloc((size_t)8192 * Kp[g] * 2);
  for (int g = 0; g < 3; ++g) wcat[g] = (ushort_t*)alloc((size_t)NCAT * Kp[g] * 2);
  ushort_t* wout = (ushort_t*)alloc((size_t)EMBED * INTER * 2);     // 8 MB
  float* bcat = (float*)alloc((size_t)NCAT * 4);
  ushort_t* rbuf = (ushort_t*)alloc((size_t)MROWS * EMBED * 2);     // 50 MB
  const bool useRB = (off <= ws_size);

  // merged preps: 2 dispatches
  const int wTotal = NCAT + EMBED * INTER + NCAT * 352;   // 6,001,664
  prep_w<<<(wTotal + 255) / 256, 256, 0, stream>>>(
      W_lin, W_res, W_out, b_lin, b_res, wout, wcat[0], wcat[1], wcat[2], bcat);
  const int xTotal = 8192 * 352;                          // 2,883,584
  prep_x<<<(xTotal + 255) / 256, 256, 0, stream>>>(
      xg[0], mg[0], tg[0], xg[1], mg[1], tg[1], xg[2], mg[2], tg[2],
      xsw[0], xsw[1], xsw[2]);

  if (useRB) {
    gemm128p1g<1><<<dim3(192, 40), 256, 0, stream>>>(
        xsw[0], xsw[1], xsw[2], wcat[0], wcat[1], wcat[2], bcat,
        hidden, out, rbuf, idxg[0], idxg[1], idxg[2]);
    gemm192x128<1><<<dim3(1024), 256, 0, stream>>>(hidden, wout, b_out, out, rbuf);
  } else {
    gemm128p1g<0><<<dim3(192, 40), 256, 0, stream>>>(
        xsw[0], xsw[1], xsw[2], wcat[0], wcat[1], wcat[2], bcat,
        hidden, out, nullptr, idxg[0], idxg[1], idxg[2]);
    gemm192x128<0><<<dim3(1024), 256, 0, stream>>>(hidden, wout, b_out, out, nullptr);
  }
}